// Round 1
// baseline (3223.463 us; speedup 1.0000x reference)
//
#include <hip/hip_runtime.h>

#define HIDDEN 2048
#define NQ     1024
#define NCTX   2048
#define NTOT   3072
#define NHEADS 32
#define KVH    8
#define HD     128

// ---------------------------------------------------------------------------
// GEMM NT: C[M,N] = A[M,K] * B[N,K]^T   (A,B row-major with K contiguous)
// 64x64 tile, BK=16, 256 threads, 4x4 micro-tile per thread.
// ---------------------------------------------------------------------------
__global__ __launch_bounds__(256) void gemm_nt(const float* __restrict__ A,
                                               const float* __restrict__ B,
                                               float* __restrict__ C,
                                               int M, int N, int K,
                                               int lda, int ldb, int ldc) {
    __shared__ float As[16][65];   // [k][m], padded
    __shared__ float Bs[16][65];   // [k][n], padded

    const int tid = threadIdx.x;
    const int bm = blockIdx.y * 64;
    const int bn = blockIdx.x * 64;
    const int tx = tid & 15;       // n quad
    const int ty = tid >> 4;       // m quad

    float acc[4][4];
#pragma unroll
    for (int i = 0; i < 4; i++)
#pragma unroll
        for (int j = 0; j < 4; j++) acc[i][j] = 0.f;

    const int lr = tid >> 2;         // 0..63 row within tile
    const int lk = (tid & 3) * 4;    // k offset 0,4,8,12
    const float* Ap = A + (long)(bm + lr) * lda + lk;
    const float* Bp = B + (long)(bn + lr) * ldb + lk;

    for (int k0 = 0; k0 < K; k0 += 16) {
        float4 a4 = *(const float4*)(Ap + k0);
        float4 b4 = *(const float4*)(Bp + k0);
        As[lk + 0][lr] = a4.x; As[lk + 1][lr] = a4.y;
        As[lk + 2][lr] = a4.z; As[lk + 3][lr] = a4.w;
        Bs[lk + 0][lr] = b4.x; Bs[lk + 1][lr] = b4.y;
        Bs[lk + 2][lr] = b4.z; Bs[lk + 3][lr] = b4.w;
        __syncthreads();
#pragma unroll
        for (int kk = 0; kk < 16; kk++) {
            float a[4], b[4];
#pragma unroll
            for (int i = 0; i < 4; i++) a[i] = As[kk][ty * 4 + i];
#pragma unroll
            for (int j = 0; j < 4; j++) b[j] = Bs[kk][tx * 4 + j];
#pragma unroll
            for (int i = 0; i < 4; i++)
#pragma unroll
                for (int j = 0; j < 4; j++) acc[i][j] += a[i] * b[j];
        }
        __syncthreads();
    }

#pragma unroll
    for (int i = 0; i < 4; i++) {
        float* Cp = C + (long)(bm + ty * 4 + i) * ldc + bn + tx * 4;
#pragma unroll
        for (int j = 0; j < 4; j++) Cp[j] = acc[i][j];
    }
}

// ---------------------------------------------------------------------------
// Fused per-head RMSNorm + RoPE, in place.
// One wave per (row, head). Lane l holds dims (l, l+64) == the RoPE pair.
// ---------------------------------------------------------------------------
__global__ __launch_bounds__(256) void rmsnorm_rope(float* __restrict__ x,
                                                    const float* __restrict__ w,
                                                    const float* __restrict__ cosb,
                                                    const float* __restrict__ sinb,
                                                    int nheads, int row_stride,
                                                    int pos_offset, int nitems) {
    int item = blockIdx.x * 4 + (threadIdx.x >> 6);
    int lane = threadIdx.x & 63;
    if (item >= nitems) return;
    int row = item / nheads;
    int head = item - row * nheads;
    float* p = x + (long)row * row_stride + head * HD;

    float x1 = p[lane], x2 = p[lane + 64];
    float ss = x1 * x1 + x2 * x2;
#pragma unroll
    for (int o = 32; o >= 1; o >>= 1) ss += __shfl_xor(ss, o);
    float r = rsqrtf(ss * (1.0f / 128.0f) + 1e-6f);

    int pos = pos_offset + row;
    float c1 = cosb[pos * HD + lane], c2 = cosb[pos * HD + lane + 64];
    float s1 = sinb[pos * HD + lane], s2 = sinb[pos * HD + lane + 64];
    float y1 = x1 * r * w[lane];
    float y2 = x2 * r * w[lane + 64];
    p[lane]      = y1 * c1 - y2 * s1;   // d < 64: x*cos - x[d+64]*sin
    p[lane + 64] = y2 * c2 + y1 * s2;   // d >=64: x*cos + x[d-64]*sin
}

// ---------------------------------------------------------------------------
// Flash attention (fp32, online softmax). Block = (head h, 64 q-rows).
// 32-key tiles; causal mask computed analytically: key t valid iff t <= CTX+qi.
// Writes output in place over the q buffer at [q, h*128 + d].
// ---------------------------------------------------------------------------
__global__ __launch_bounds__(256) void flash_attn(const float* __restrict__ qb,
                                                  const float* __restrict__ kb,
                                                  const float* __restrict__ vb,
                                                  float* __restrict__ ob) {
    __shared__ float Qs[64][129];
    __shared__ float Ks[32][129];
    __shared__ float Vs[32][129];
    __shared__ float Ss[64][33];
    __shared__ float mrow[64], lrow[64], arow[64];

    const int tid = threadIdx.x;
    const int h = blockIdx.x;
    const int qt = blockIdx.y;
    const int g = h >> 2;                      // kv head
    const float* Qp = qb + (long)(qt * 64) * 4096 + h * 128;
    const float* Kp = kb + g * 128;            // row stride 1024
    const float* Vp = vb + g * 128;

    const float scale = 0.08838834764831845f;  // 1/sqrt(128)

    // load Q tile (pre-scaled)
#pragma unroll
    for (int i = 0; i < 8; i++) {
        int idx = tid + i * 256;               // float4 units, 0..2047
        int r = idx >> 5, c4 = (idx & 31) * 4;
        float4 q4 = *(const float4*)(Qp + (long)r * 4096 + c4);
        Qs[r][c4 + 0] = q4.x * scale; Qs[r][c4 + 1] = q4.y * scale;
        Qs[r][c4 + 2] = q4.z * scale; Qs[r][c4 + 3] = q4.w * scale;
    }
    const int r  = tid >> 2;                   // q row 0..63
    const int dl = tid & 3;                    // d interleave phase
    if (dl == 0) { mrow[r] = -1e30f; lrow[r] = 0.f; }
    float o[32];
#pragma unroll
    for (int j = 0; j < 32; j++) o[j] = 0.f;
    __syncthreads();

    const int ntiles = 66 + qt * 2;            // (2048 + qt*64 + 64)/32
    const int tlim = 2048 + qt * 64 + r;       // last valid key for this row

    for (int tile = 0; tile < ntiles; tile++) {
        const int t0 = tile * 32;
        // load K/V tiles
#pragma unroll
        for (int i = 0; i < 4; i++) {
            int idx = tid + i * 256;           // float4 units, 0..1023
            int rr = idx >> 5, c4 = (idx & 31) * 4;
            float4 k4 = *(const float4*)(Kp + (long)(t0 + rr) * 1024 + c4);
            Ks[rr][c4 + 0] = k4.x; Ks[rr][c4 + 1] = k4.y;
            Ks[rr][c4 + 2] = k4.z; Ks[rr][c4 + 3] = k4.w;
            float4 v4 = *(const float4*)(Vp + (long)(t0 + rr) * 1024 + c4);
            Vs[rr][c4 + 0] = v4.x; Vs[rr][c4 + 1] = v4.y;
            Vs[rr][c4 + 2] = v4.z; Vs[rr][c4 + 3] = v4.w;
        }
        __syncthreads();

        // scores: this thread computes S[r][cbase..cbase+7]
        const int cbase = dl * 8;
        float sc[8];
#pragma unroll
        for (int j = 0; j < 8; j++) sc[j] = 0.f;
        for (int d = 0; d < 128; d++) {
            float qv = Qs[r][d];
#pragma unroll
            for (int j = 0; j < 8; j++) sc[j] += qv * Ks[cbase + j][d];
        }
#pragma unroll
        for (int j = 0; j < 8; j++) {
            int t = t0 + cbase + j;
            Ss[r][cbase + j] = (t <= tlim) ? sc[j] : -1e30f;
        }
        __syncthreads();

        // online softmax (one thread per row)
        if (dl == 0) {
            float mold = mrow[r];
            float tmax = -1e30f;
#pragma unroll
            for (int c = 0; c < 32; c++) tmax = fmaxf(tmax, Ss[r][c]);
            float mnew = fmaxf(mold, tmax);
            float alpha = __expf(mold - mnew);
            float sum = 0.f;
#pragma unroll
            for (int c = 0; c < 32; c++) {
                float p = __expf(Ss[r][c] - mnew);
                Ss[r][c] = p;
                sum += p;
            }
            lrow[r] = lrow[r] * alpha + sum;
            mrow[r] = mnew;
            arow[r] = alpha;
        }
        __syncthreads();

        // PV accumulate: thread owns d = dl + 4*j
        float alpha = arow[r];
#pragma unroll
        for (int j = 0; j < 32; j++) o[j] *= alpha;
        for (int c = 0; c < 32; c++) {
            float p = Ss[r][c];
#pragma unroll
            for (int j = 0; j < 32; j++) o[j] += p * Vs[c][dl + 4 * j];
        }
        __syncthreads();
    }

    float inv = 1.0f / lrow[r];
    float* Op = ob + (long)(qt * 64 + r) * 4096 + h * 128 + dl;
#pragma unroll
    for (int j = 0; j < 32; j++) Op[4 * j] = o[j] * inv;
}

// ---------------------------------------------------------------------------
extern "C" void kernel_launch(void* const* d_in, const int* in_sizes, int n_in,
                              void* d_out, int out_size, void* d_ws, size_t ws_size,
                              hipStream_t stream) {
    const float* hidden = (const float*)d_in[0];   // (1,1024,2048)
    const float* target = (const float*)d_in[1];   // (1,2048,2048)
    const float* cosb   = (const float*)d_in[2];   // (1,3072,128)
    const float* sinb   = (const float*)d_in[3];   // (1,3072,128)
    // d_in[4] = attention_mask (bool) — reconstructed analytically, unused
    const float* wq = (const float*)d_in[5];       // (4096,2048)
    const float* wk = (const float*)d_in[6];       // (1024,2048)
    const float* wv = (const float*)d_in[7];       // (1024,2048)
    const float* wo = (const float*)d_in[8];       // (2048,4096)
    const float* qw = (const float*)d_in[9];       // (128,)
    const float* kw = (const float*)d_in[10];      // (128,)
    float* out = (float*)d_out;                    // (1024,2048) fp32

    float* qbuf = (float*)d_ws;                    // 1024*4096 (q, then attn out)
    float* kbuf = qbuf + 1024 * 4096;              // 3072*1024
    float* vbuf = kbuf + 3072 * 1024;              // 3072*1024

    dim3 blk(256);

    // q = hidden @ wq^T  -> (1024,4096)
    gemm_nt<<<dim3(4096 / 64, 1024 / 64), blk, 0, stream>>>(
        hidden, wq, qbuf, 1024, 4096, 2048, 2048, 2048, 4096);
    // k = [target; hidden] @ wk^T -> (3072,1024)
    gemm_nt<<<dim3(1024 / 64, 2048 / 64), blk, 0, stream>>>(
        target, wk, kbuf, 2048, 1024, 2048, 2048, 2048, 1024);
    gemm_nt<<<dim3(1024 / 64, 1024 / 64), blk, 0, stream>>>(
        hidden, wk, kbuf + 2048 * 1024, 1024, 1024, 2048, 2048, 2048, 1024);
    // v = [target; hidden] @ wv^T -> (3072,1024)
    gemm_nt<<<dim3(1024 / 64, 2048 / 64), blk, 0, stream>>>(
        target, wv, vbuf, 2048, 1024, 2048, 2048, 2048, 1024);
    gemm_nt<<<dim3(1024 / 64, 1024 / 64), blk, 0, stream>>>(
        hidden, wv, vbuf + 2048 * 1024, 1024, 1024, 2048, 2048, 2048, 1024);

    // RMSNorm + RoPE (in place). q positions are CTX..CTX+Q-1, k positions 0..T-1.
    rmsnorm_rope<<<(1024 * 32) / 4, blk, 0, stream>>>(qbuf, qw, cosb, sinb,
                                                      32, 4096, 2048, 1024 * 32);
    rmsnorm_rope<<<(3072 * 8) / 4, blk, 0, stream>>>(kbuf, kw, cosb, sinb,
                                                     8, 1024, 0, 3072 * 8);

    // flash attention, output in place over qbuf
    flash_attn<<<dim3(32, 16), blk, 0, stream>>>(qbuf, kbuf, vbuf, qbuf);

    // final = attn_out @ wo^T -> (1024,2048)
    gemm_nt<<<dim3(2048 / 64, 1024 / 64), blk, 0, stream>>>(
        qbuf, wo, out, 1024, 2048, 4096, 4096, 4096, 2048);
}

// Round 2
// 1734.613 us; speedup vs baseline: 1.8583x; 1.8583x over previous
//
#include <hip/hip_runtime.h>

#define HIDDEN 2048
#define NQ     1024
#define NCTX   2048
#define NTOT   3072
#define NHEADS 32
#define KVH    8
#define HD     128

typedef __attribute__((ext_vector_type(8))) __bf16 bf16x8;
typedef __attribute__((ext_vector_type(4))) __bf16 bf16x4;
typedef __attribute__((ext_vector_type(4))) float  f32x4;

#define MFMA16(a, b, c) __builtin_amdgcn_mfma_f32_16x16x32_bf16(a, b, c, 0, 0, 0)

// ---------------------------------------------------------------------------
// GEMM NT fp32: C[M,N] = A[M,K] * B[N,K]^T  (used for final wo projection)
// ---------------------------------------------------------------------------
__global__ __launch_bounds__(256) void gemm_nt(const float* __restrict__ A,
                                               const float* __restrict__ B,
                                               float* __restrict__ C,
                                               int M, int N, int K,
                                               int lda, int ldb, int ldc) {
    __shared__ float As[16][65];
    __shared__ float Bs[16][65];
    const int tid = threadIdx.x;
    const int bm = blockIdx.y * 64;
    const int bn = blockIdx.x * 64;
    const int tx = tid & 15;
    const int ty = tid >> 4;
    float acc[4][4];
#pragma unroll
    for (int i = 0; i < 4; i++)
#pragma unroll
        for (int j = 0; j < 4; j++) acc[i][j] = 0.f;
    const int lr = tid >> 2;
    const int lk = (tid & 3) * 4;
    const float* Ap = A + (long)(bm + lr) * lda + lk;
    const float* Bp = B + (long)(bn + lr) * ldb + lk;
    for (int k0 = 0; k0 < K; k0 += 16) {
        float4 a4 = *(const float4*)(Ap + k0);
        float4 b4 = *(const float4*)(Bp + k0);
        As[lk + 0][lr] = a4.x; As[lk + 1][lr] = a4.y;
        As[lk + 2][lr] = a4.z; As[lk + 3][lr] = a4.w;
        Bs[lk + 0][lr] = b4.x; Bs[lk + 1][lr] = b4.y;
        Bs[lk + 2][lr] = b4.z; Bs[lk + 3][lr] = b4.w;
        __syncthreads();
#pragma unroll
        for (int kk = 0; kk < 16; kk++) {
            float a[4], b[4];
#pragma unroll
            for (int i = 0; i < 4; i++) a[i] = As[kk][ty * 4 + i];
#pragma unroll
            for (int j = 0; j < 4; j++) b[j] = Bs[kk][tx * 4 + j];
#pragma unroll
            for (int i = 0; i < 4; i++)
#pragma unroll
                for (int j = 0; j < 4; j++) acc[i][j] += a[i] * b[j];
        }
        __syncthreads();
    }
#pragma unroll
    for (int i = 0; i < 4; i++) {
        float* Cp = C + (long)(bm + ty * 4 + i) * ldc + bn + tx * 4;
#pragma unroll
        for (int j = 0; j < 4; j++) Cp[j] = acc[i][j];
    }
}

// ---------------------------------------------------------------------------
// GEMM NT with bf16 output (q/k/v projections)
// ---------------------------------------------------------------------------
__global__ __launch_bounds__(256) void gemm_nt_bf16(const float* __restrict__ A,
                                                    const float* __restrict__ B,
                                                    __bf16* __restrict__ C,
                                                    int M, int N, int K,
                                                    int lda, int ldb, int ldc) {
    __shared__ float As[16][65];
    __shared__ float Bs[16][65];
    const int tid = threadIdx.x;
    const int bm = blockIdx.y * 64;
    const int bn = blockIdx.x * 64;
    const int tx = tid & 15;
    const int ty = tid >> 4;
    float acc[4][4];
#pragma unroll
    for (int i = 0; i < 4; i++)
#pragma unroll
        for (int j = 0; j < 4; j++) acc[i][j] = 0.f;
    const int lr = tid >> 2;
    const int lk = (tid & 3) * 4;
    const float* Ap = A + (long)(bm + lr) * lda + lk;
    const float* Bp = B + (long)(bn + lr) * ldb + lk;
    for (int k0 = 0; k0 < K; k0 += 16) {
        float4 a4 = *(const float4*)(Ap + k0);
        float4 b4 = *(const float4*)(Bp + k0);
        As[lk + 0][lr] = a4.x; As[lk + 1][lr] = a4.y;
        As[lk + 2][lr] = a4.z; As[lk + 3][lr] = a4.w;
        Bs[lk + 0][lr] = b4.x; Bs[lk + 1][lr] = b4.y;
        Bs[lk + 2][lr] = b4.z; Bs[lk + 3][lr] = b4.w;
        __syncthreads();
#pragma unroll
        for (int kk = 0; kk < 16; kk++) {
            float a[4], b[4];
#pragma unroll
            for (int i = 0; i < 4; i++) a[i] = As[kk][ty * 4 + i];
#pragma unroll
            for (int j = 0; j < 4; j++) b[j] = Bs[kk][tx * 4 + j];
#pragma unroll
            for (int i = 0; i < 4; i++)
#pragma unroll
                for (int j = 0; j < 4; j++) acc[i][j] += a[i] * b[j];
        }
        __syncthreads();
    }
#pragma unroll
    for (int i = 0; i < 4; i++) {
        __bf16* Cp = C + (long)(bm + ty * 4 + i) * ldc + bn + tx * 4;
        bf16x4 o;
#pragma unroll
        for (int j = 0; j < 4; j++) o[j] = (__bf16)acc[i][j];
        *(bf16x4*)Cp = o;
    }
}

// ---------------------------------------------------------------------------
// Fused per-head RMSNorm + RoPE on bf16, in place. outscale folds 1/sqrt(HD)
// for q. One wave per (row, head); lane l holds the RoPE pair (l, l+64).
// ---------------------------------------------------------------------------
__global__ __launch_bounds__(256) void rmsnorm_rope_bf16(__bf16* __restrict__ x,
                                                         const float* __restrict__ w,
                                                         const float* __restrict__ cosb,
                                                         const float* __restrict__ sinb,
                                                         int nheads, int row_stride,
                                                         int pos_offset, float outscale,
                                                         int nitems) {
    int item = blockIdx.x * 4 + (threadIdx.x >> 6);
    int lane = threadIdx.x & 63;
    if (item >= nitems) return;
    int row = item / nheads;
    int head = item - row * nheads;
    __bf16* p = x + (long)row * row_stride + head * HD;

    float x1 = (float)p[lane], x2 = (float)p[lane + 64];
    float ss = x1 * x1 + x2 * x2;
#pragma unroll
    for (int o = 32; o >= 1; o >>= 1) ss += __shfl_xor(ss, o);
    float r = rsqrtf(ss * (1.0f / 128.0f) + 1e-6f) * outscale;

    int pos = pos_offset + row;
    float c1 = cosb[pos * HD + lane], c2 = cosb[pos * HD + lane + 64];
    float s1 = sinb[pos * HD + lane], s2 = sinb[pos * HD + lane + 64];
    float y1 = x1 * r * w[lane];
    float y2 = x2 * r * w[lane + 64];
    p[lane]      = (__bf16)(y1 * c1 - y2 * s1);
    p[lane + 64] = (__bf16)(y2 * c2 + y1 * s2);
}

// ---------------------------------------------------------------------------
// V transpose: vbf[t][kvh*128+d] -> vt[kvh][d][t]   (64x64 LDS tiles)
// ---------------------------------------------------------------------------
__global__ __launch_bounds__(256) void transpose_v(const __bf16* __restrict__ v,
                                                   __bf16* __restrict__ vt) {
    __shared__ __bf16 T[64][68];
    const int tid = threadIdx.x;
    const int t0 = blockIdx.x * 64;
    const int d0 = blockIdx.y * 64;
    const int g  = blockIdx.z;
    const __bf16* src = v + (long)t0 * 1024 + g * 128 + d0;
#pragma unroll
    for (int i = 0; i < 4; i++) {
        int idx = tid + i * 256;
        int r = idx >> 4, c4 = (idx & 15) * 4;
        *(bf16x4*)&T[r][c4] = *(const bf16x4*)(src + (long)r * 1024 + c4);
    }
    __syncthreads();
    __bf16* dst = vt + (long)g * 128 * 3072 + (long)d0 * 3072 + t0;
#pragma unroll
    for (int i = 0; i < 4; i++) {
        int idx = tid + i * 256;
        int r = idx >> 4, c4 = (idx & 15) * 4;   // r: d-local, c4: t-local
        bf16x4 o;
        o[0] = T[c4 + 0][r]; o[1] = T[c4 + 1][r];
        o[2] = T[c4 + 2][r]; o[3] = T[c4 + 3][r];
        *(bf16x4*)(dst + (long)r * 3072 + c4) = o;
    }
}

// ---------------------------------------------------------------------------
// MFMA flash attention. Block = (head, 64 q rows), 4 waves x 16 q rows.
// Q frags in registers; K in LDS [t][d]; V pre-transposed [d][t]; P through
// per-wave LDS for C-layout -> A-layout. Softmax stats in registers.
// ---------------------------------------------------------------------------
__global__ __launch_bounds__(256) void flash_attn_mfma(const __bf16* __restrict__ qb,
                                                       const __bf16* __restrict__ kb,
                                                       const __bf16* __restrict__ vtg,
                                                       float* __restrict__ ob) {
    __shared__ __bf16 Ks[64][136];     // [t][d]
    __shared__ __bf16 Vs[128][72];     // [d][t]
    __shared__ __bf16 Ps[4][16][72];   // per wave [m][t]

    const int tid  = threadIdx.x;
    const int lane = tid & 63;
    const int w    = tid >> 6;
    const int n    = lane & 15;
    const int quad = lane >> 4;

    const int bid = blockIdx.x;
    const int g  = bid & 7;            // kv head (XCD-swizzled)
    const int jj = bid >> 3;
    const int h  = g * 4 + (jj & 3);
    const int qt = jj >> 2;

    const int qbase = qt * 64 + w * 16;

    // Q A-fragments, resident for the whole loop (scaled by rsqrt(HD) upstream)
    bf16x8 qf[4];
    {
        const __bf16* qp = qb + (long)(qbase + n) * 4096 + h * 128 + quad * 8;
        qf[0] = *(const bf16x8*)(qp);
        qf[1] = *(const bf16x8*)(qp + 32);
        qf[2] = *(const bf16x8*)(qp + 64);
        qf[3] = *(const bf16x8*)(qp + 96);
    }

    f32x4 O[8];
    const f32x4 fzero = {0.f, 0.f, 0.f, 0.f};
#pragma unroll
    for (int dt = 0; dt < 8; dt++) O[dt] = fzero;
    float m_i[4], l_i[4];
#pragma unroll
    for (int r = 0; r < 4; r++) { m_i[r] = -1e30f; l_i[r] = 0.f; }

    const __bf16* Kg = kb + g * 128;                 // row stride 1024
    const __bf16* Vg = vtg + (long)g * 128 * 3072;   // row stride 3072

    const int ntiles = 33 + qt;
    for (int tt = 0; tt < ntiles; tt++) {
        const int t0 = tt * 64;
        // stage K tile 64x128
#pragma unroll
        for (int i = 0; i < 4; i++) {
            int idx = tid + i * 256;
            int rr = idx >> 4, c8 = (idx & 15) * 8;
            *(bf16x8*)&Ks[rr][c8] = *(const bf16x8*)(Kg + (long)(t0 + rr) * 1024 + c8);
        }
        // stage V^T tile 128x64
#pragma unroll
        for (int i = 0; i < 4; i++) {
            int idx = tid + i * 256;
            int rr = idx >> 3, c8 = (idx & 7) * 8;
            *(bf16x8*)&Vs[rr][c8] = *(const bf16x8*)(Vg + (long)rr * 3072 + t0 + c8);
        }
        __syncthreads();

        // S = Q K^T : 4 tiles of 16 keys
        f32x4 S[4];
#pragma unroll
        for (int nt = 0; nt < 4; nt++) {
            f32x4 acc = fzero;
#pragma unroll
            for (int ks = 0; ks < 4; ks++)
                acc = MFMA16(qf[ks], *(const bf16x8*)&Ks[nt * 16 + n][ks * 32 + quad * 8], acc);
            S[nt] = acc;
        }

        // causal mask: only the final (diagonal) tile needs it
        if (tt == ntiles - 1) {
#pragma unroll
            for (int nt = 0; nt < 4; nt++)
#pragma unroll
                for (int r = 0; r < 4; r++) {
                    int t   = t0 + nt * 16 + n;
                    int lim = 2048 + qbase + quad * 4 + r;
                    if (t > lim) S[nt][r] = -1e30f;
                }
        }

        // online softmax (rows live in registers across 16 lanes)
        float alpha[4], mnew[4];
#pragma unroll
        for (int r = 0; r < 4; r++) {
            float mx = fmaxf(fmaxf(S[0][r], S[1][r]), fmaxf(S[2][r], S[3][r]));
            mx = fmaxf(mx, __shfl_xor(mx, 1));
            mx = fmaxf(mx, __shfl_xor(mx, 2));
            mx = fmaxf(mx, __shfl_xor(mx, 4));
            mx = fmaxf(mx, __shfl_xor(mx, 8));
            mnew[r]  = fmaxf(m_i[r], mx);
            alpha[r] = __expf(m_i[r] - mnew[r]);
            m_i[r]   = mnew[r];
        }
        float rsum[4] = {0.f, 0.f, 0.f, 0.f};
#pragma unroll
        for (int nt = 0; nt < 4; nt++)
#pragma unroll
            for (int r = 0; r < 4; r++) {
                float p = __expf(S[nt][r] - mnew[r]);
                S[nt][r] = p;
                rsum[r] += p;
            }
#pragma unroll
        for (int r = 0; r < 4; r++) {
            float s = rsum[r];
            s += __shfl_xor(s, 1);
            s += __shfl_xor(s, 2);
            s += __shfl_xor(s, 4);
            s += __shfl_xor(s, 8);
            l_i[r] = l_i[r] * alpha[r] + s;
        }

        // P -> LDS (C-layout -> A-layout round trip)
#pragma unroll
        for (int nt = 0; nt < 4; nt++)
#pragma unroll
            for (int r = 0; r < 4; r++)
                Ps[w][quad * 4 + r][nt * 16 + n] = (__bf16)S[nt][r];

        // rescale O
#pragma unroll
        for (int dt = 0; dt < 8; dt++)
#pragma unroll
            for (int r = 0; r < 4; r++) O[dt][r] *= alpha[r];

        // O += P V
        bf16x8 pa0 = *(const bf16x8*)&Ps[w][n][quad * 8];
        bf16x8 pa1 = *(const bf16x8*)&Ps[w][n][32 + quad * 8];
#pragma unroll
        for (int dt = 0; dt < 8; dt++) {
            f32x4 acc = O[dt];
            acc = MFMA16(pa0, *(const bf16x8*)&Vs[dt * 16 + n][quad * 8], acc);
            acc = MFMA16(pa1, *(const bf16x8*)&Vs[dt * 16 + n][32 + quad * 8], acc);
            O[dt] = acc;
        }
        __syncthreads();
    }

    // epilogue: normalize and store fp32
    float inv[4];
#pragma unroll
    for (int r = 0; r < 4; r++) inv[r] = 1.0f / l_i[r];
#pragma unroll
    for (int dt = 0; dt < 8; dt++)
#pragma unroll
        for (int r = 0; r < 4; r++)
            ob[(long)(qbase + quad * 4 + r) * 4096 + h * 128 + dt * 16 + n] = O[dt][r] * inv[r];
}

// ---------------------------------------------------------------------------
extern "C" void kernel_launch(void* const* d_in, const int* in_sizes, int n_in,
                              void* d_out, int out_size, void* d_ws, size_t ws_size,
                              hipStream_t stream) {
    const float* hidden = (const float*)d_in[0];
    const float* target = (const float*)d_in[1];
    const float* cosb   = (const float*)d_in[2];
    const float* sinb   = (const float*)d_in[3];
    const float* wq = (const float*)d_in[5];
    const float* wk = (const float*)d_in[6];
    const float* wv = (const float*)d_in[7];
    const float* wo = (const float*)d_in[8];
    const float* qw = (const float*)d_in[9];
    const float* kw = (const float*)d_in[10];
    float* out = (float*)d_out;

    char* ws = (char*)d_ws;
    __bf16* qbf  = (__bf16*)(ws);                        // 8 MB  [1024][4096]
    __bf16* kbf  = (__bf16*)(ws + (8ll << 20));          // 6 MB  [3072][1024]
    __bf16* vbf  = (__bf16*)(ws + (14ll << 20));         // 6 MB  [3072][1024] (dead after transpose)
    float*  aout = (float*)(ws + (14ll << 20));          // 16 MB [1024][4096] (overlays vbf)
    __bf16* vtg  = (__bf16*)(ws + (30ll << 20));         // 6 MB  [8][128][3072]

    dim3 blk(256);

    // projections (fp32 GEMM, bf16 out)
    gemm_nt_bf16<<<dim3(64, 16), blk, 0, stream>>>(hidden, wq, qbf, 1024, 4096, 2048, 2048, 2048, 4096);
    gemm_nt_bf16<<<dim3(16, 32), blk, 0, stream>>>(target, wk, kbf, 2048, 1024, 2048, 2048, 2048, 1024);
    gemm_nt_bf16<<<dim3(16, 16), blk, 0, stream>>>(hidden, wk, kbf + 2048ll * 1024, 1024, 1024, 2048, 2048, 2048, 1024);
    gemm_nt_bf16<<<dim3(16, 32), blk, 0, stream>>>(target, wv, vbf, 2048, 1024, 2048, 2048, 2048, 1024);
    gemm_nt_bf16<<<dim3(16, 16), blk, 0, stream>>>(hidden, wv, vbf + 2048ll * 1024, 1024, 1024, 2048, 2048, 2048, 1024);

    // RMSNorm + RoPE in place (q gets the 1/sqrt(HD) fold)
    rmsnorm_rope_bf16<<<(1024 * 32) / 4, blk, 0, stream>>>(qbf, qw, cosb, sinb,
                                                           32, 4096, 2048, 0.08838834764831845f, 1024 * 32);
    rmsnorm_rope_bf16<<<(3072 * 8) / 4, blk, 0, stream>>>(kbf, kw, cosb, sinb,
                                                          8, 1024, 0, 1.0f, 3072 * 8);

    // V transpose to [kvh][d][t]
    transpose_v<<<dim3(48, 2, 8), blk, 0, stream>>>(vbf, vtg);

    // MFMA flash attention -> aout (fp32)
    flash_attn_mfma<<<dim3(512), blk, 0, stream>>>(qbf, kbf, vtg, aout);

    // final projection (fp32)
    gemm_nt<<<dim3(32, 16), blk, 0, stream>>>(aout, wo, out, 1024, 2048, 4096, 4096, 4096, 2048);
}

// Round 3
// 709.574 us; speedup vs baseline: 4.5428x; 2.4446x over previous
//
#include <hip/hip_runtime.h>

#define HIDDEN 2048
#define NQ     1024
#define NCTX   2048
#define NTOT   3072
#define NHEADS 32
#define KVH    8
#define HD     128

typedef __attribute__((ext_vector_type(8))) __bf16 bf16x8;
typedef __attribute__((ext_vector_type(4))) __bf16 bf16x4;
typedef __attribute__((ext_vector_type(4))) float  f32x4;

#define MFMA16(a, b, c) __builtin_amdgcn_mfma_f32_16x16x32_bf16(a, b, c, 0, 0, 0)

// async global->LDS, 16B per lane. HW semantics: wave-uniform base + lane*16;
// our per-lane lds pointers are constructed to equal exactly that.
__device__ __forceinline__ void load_lds16(const void* g, void* l) {
    __builtin_amdgcn_global_load_lds(
        (const __attribute__((address_space(1))) unsigned int*)g,
        (__attribute__((address_space(3))) unsigned int*)l, 16, 0, 0);
}

// ---------------------------------------------------------------------------
// fp32 -> bf16 elementwise convert (float4 granularity)
// ---------------------------------------------------------------------------
__global__ __launch_bounds__(256) void conv_f32_bf16(const float* __restrict__ src,
                                                     __bf16* __restrict__ dst, int n4) {
    int i = blockIdx.x * 256 + threadIdx.x;
    int stride = gridDim.x * 256;
    for (; i < n4; i += stride) {
        float4 v = ((const float4*)src)[i];
        bf16x4 o;
        o[0] = (__bf16)v.x; o[1] = (__bf16)v.y;
        o[2] = (__bf16)v.z; o[3] = (__bf16)v.w;
        ((bf16x4*)dst)[i] = o;
    }
}

// ---------------------------------------------------------------------------
// MFMA GEMM NT: C[M,N] = A[M,K] * B[N,K]^T, all bf16 in, OutT out.
// 128x128 tile, BK=64, 256 threads (4 waves, 2x2), global_load_lds staging.
// M,N multiples of 128; K multiple of 64.
// ---------------------------------------------------------------------------
template <typename OutT>
__global__ __launch_bounds__(256) void gemm_bt_mfma(const __bf16* __restrict__ A,
                                                    const __bf16* __restrict__ B,
                                                    OutT* __restrict__ C,
                                                    int M, int N, int K,
                                                    int lda, int ldb, int ldc) {
    __shared__ __bf16 As[128][64];   // unpadded: global_load_lds layout constraint
    __shared__ __bf16 Bs[128][64];

    const int tid  = threadIdx.x;
    const int lane = tid & 63;
    const int w    = tid >> 6;
    const int n16  = lane & 15;
    const int quad = lane >> 4;
    const int m0 = blockIdx.y * 128;
    const int n0 = blockIdx.x * 128;
    const int wm = (w & 1) * 64;
    const int wn = (w >> 1) * 64;

    f32x4 acc[4][4];
    const f32x4 fzero = {0.f, 0.f, 0.f, 0.f};
#pragma unroll
    for (int i = 0; i < 4; i++)
#pragma unroll
        for (int j = 0; j < 4; j++) acc[i][j] = fzero;

    const __bf16* Ablk = A + (long)m0 * lda;
    const __bf16* Bblk = B + (long)n0 * ldb;
    const int srow = w * 32 + (lane >> 3);   // staging row for this lane
    const int scol = (lane & 7) * 8;         // staging col (bf16 elements)

    for (int k0 = 0; k0 < K; k0 += 64) {
#pragma unroll
        for (int i = 0; i < 4; i++) {
            int r = srow + i * 8;
            load_lds16(Ablk + (long)r * lda + k0 + scol, &As[r][scol]);
            load_lds16(Bblk + (long)r * ldb + k0 + scol, &Bs[r][scol]);
        }
        __syncthreads();
#pragma unroll
        for (int ks = 0; ks < 2; ks++) {
            bf16x8 af[4], bfr[4];
#pragma unroll
            for (int i = 0; i < 4; i++)
                af[i] = *(const bf16x8*)&As[wm + i * 16 + n16][ks * 32 + quad * 8];
#pragma unroll
            for (int j = 0; j < 4; j++)
                bfr[j] = *(const bf16x8*)&Bs[wn + j * 16 + n16][ks * 32 + quad * 8];
#pragma unroll
            for (int i = 0; i < 4; i++)
#pragma unroll
                for (int j = 0; j < 4; j++)
                    acc[i][j] = MFMA16(af[i], bfr[j], acc[i][j]);
        }
        __syncthreads();
    }

#pragma unroll
    for (int i = 0; i < 4; i++)
#pragma unroll
        for (int j = 0; j < 4; j++)
#pragma unroll
            for (int r = 0; r < 4; r++)
                C[(long)(m0 + wm + i * 16 + quad * 4 + r) * ldc + n0 + wn + j * 16 + n16] =
                    (OutT)acc[i][j][r];
}

// ---------------------------------------------------------------------------
// Fused per-head RMSNorm + RoPE on bf16, in place.
// ---------------------------------------------------------------------------
__global__ __launch_bounds__(256) void rmsnorm_rope_bf16(__bf16* __restrict__ x,
                                                         const float* __restrict__ w,
                                                         const float* __restrict__ cosb,
                                                         const float* __restrict__ sinb,
                                                         int nheads, int row_stride,
                                                         int pos_offset, float outscale,
                                                         int nitems) {
    int item = blockIdx.x * 4 + (threadIdx.x >> 6);
    int lane = threadIdx.x & 63;
    if (item >= nitems) return;
    int row = item / nheads;
    int head = item - row * nheads;
    __bf16* p = x + (long)row * row_stride + head * HD;

    float x1 = (float)p[lane], x2 = (float)p[lane + 64];
    float ss = x1 * x1 + x2 * x2;
#pragma unroll
    for (int o = 32; o >= 1; o >>= 1) ss += __shfl_xor(ss, o);
    float r = rsqrtf(ss * (1.0f / 128.0f) + 1e-6f) * outscale;

    int pos = pos_offset + row;
    float c1 = cosb[pos * HD + lane], c2 = cosb[pos * HD + lane + 64];
    float s1 = sinb[pos * HD + lane], s2 = sinb[pos * HD + lane + 64];
    float y1 = x1 * r * w[lane];
    float y2 = x2 * r * w[lane + 64];
    p[lane]      = (__bf16)(y1 * c1 - y2 * s1);
    p[lane + 64] = (__bf16)(y2 * c2 + y1 * s2);
}

// ---------------------------------------------------------------------------
// V transpose: vbf[t][kvh*128+d] -> vt[kvh][d][t]
// ---------------------------------------------------------------------------
__global__ __launch_bounds__(256) void transpose_v(const __bf16* __restrict__ v,
                                                   __bf16* __restrict__ vt) {
    __shared__ __bf16 T[64][68];
    const int tid = threadIdx.x;
    const int t0 = blockIdx.x * 64;
    const int d0 = blockIdx.y * 64;
    const int g  = blockIdx.z;
    const __bf16* src = v + (long)t0 * 1024 + g * 128 + d0;
#pragma unroll
    for (int i = 0; i < 4; i++) {
        int idx = tid + i * 256;
        int r = idx >> 4, c4 = (idx & 15) * 4;
        *(bf16x4*)&T[r][c4] = *(const bf16x4*)(src + (long)r * 1024 + c4);
    }
    __syncthreads();
    __bf16* dst = vt + (long)g * 128 * 3072 + (long)d0 * 3072 + t0;
#pragma unroll
    for (int i = 0; i < 4; i++) {
        int idx = tid + i * 256;
        int r = idx >> 4, c4 = (idx & 15) * 4;
        bf16x4 o;
        o[0] = T[c4 + 0][r]; o[1] = T[c4 + 1][r];
        o[2] = T[c4 + 2][r]; o[3] = T[c4 + 3][r];
        *(bf16x4*)(dst + (long)r * 3072 + c4) = o;
    }
}

// ---------------------------------------------------------------------------
// MFMA flash attention. Block = (head, 64 q rows), 4 waves x 16 q rows.
// Writes bf16 output IN PLACE over the q buffer (each block reads its own
// slice into registers before any writes).
// ---------------------------------------------------------------------------
__global__ __launch_bounds__(256) void flash_attn_mfma(const __bf16* __restrict__ qb,
                                                       const __bf16* __restrict__ kb,
                                                       const __bf16* __restrict__ vtg,
                                                       __bf16* __restrict__ ob) {
    __shared__ __bf16 Ks[64][136];     // [t][d]
    __shared__ __bf16 Vs[128][72];     // [d][t]
    __shared__ __bf16 Ps[4][16][72];   // per wave [m][t]

    const int tid  = threadIdx.x;
    const int lane = tid & 63;
    const int w    = tid >> 6;
    const int n    = lane & 15;
    const int quad = lane >> 4;

    const int bid = blockIdx.x;
    const int g  = bid & 7;
    const int jj = bid >> 3;
    const int h  = g * 4 + (jj & 3);
    const int qt = jj >> 2;

    const int qbase = qt * 64 + w * 16;

    bf16x8 qf[4];
    {
        const __bf16* qp = qb + (long)(qbase + n) * 4096 + h * 128 + quad * 8;
        qf[0] = *(const bf16x8*)(qp);
        qf[1] = *(const bf16x8*)(qp + 32);
        qf[2] = *(const bf16x8*)(qp + 64);
        qf[3] = *(const bf16x8*)(qp + 96);
    }

    f32x4 O[8];
    const f32x4 fzero = {0.f, 0.f, 0.f, 0.f};
#pragma unroll
    for (int dt = 0; dt < 8; dt++) O[dt] = fzero;
    float m_i[4], l_i[4];
#pragma unroll
    for (int r = 0; r < 4; r++) { m_i[r] = -1e30f; l_i[r] = 0.f; }

    const __bf16* Kg = kb + g * 128;
    const __bf16* Vg = vtg + (long)g * 128 * 3072;

    const int ntiles = 33 + qt;
    for (int tt = 0; tt < ntiles; tt++) {
        const int t0 = tt * 64;
#pragma unroll
        for (int i = 0; i < 4; i++) {
            int idx = tid + i * 256;
            int rr = idx >> 4, c8 = (idx & 15) * 8;
            *(bf16x8*)&Ks[rr][c8] = *(const bf16x8*)(Kg + (long)(t0 + rr) * 1024 + c8);
        }
#pragma unroll
        for (int i = 0; i < 4; i++) {
            int idx = tid + i * 256;
            int rr = idx >> 3, c8 = (idx & 7) * 8;
            *(bf16x8*)&Vs[rr][c8] = *(const bf16x8*)(Vg + (long)rr * 3072 + t0 + c8);
        }
        __syncthreads();

        f32x4 S[4];
#pragma unroll
        for (int nt = 0; nt < 4; nt++) {
            f32x4 acc = fzero;
#pragma unroll
            for (int ks = 0; ks < 4; ks++)
                acc = MFMA16(qf[ks], *(const bf16x8*)&Ks[nt * 16 + n][ks * 32 + quad * 8], acc);
            S[nt] = acc;
        }

        if (tt == ntiles - 1) {
#pragma unroll
            for (int nt = 0; nt < 4; nt++)
#pragma unroll
                for (int r = 0; r < 4; r++) {
                    int t   = t0 + nt * 16 + n;
                    int lim = 2048 + qbase + quad * 4 + r;
                    if (t > lim) S[nt][r] = -1e30f;
                }
        }

        float alpha[4], mnew[4];
#pragma unroll
        for (int r = 0; r < 4; r++) {
            float mx = fmaxf(fmaxf(S[0][r], S[1][r]), fmaxf(S[2][r], S[3][r]));
            mx = fmaxf(mx, __shfl_xor(mx, 1));
            mx = fmaxf(mx, __shfl_xor(mx, 2));
            mx = fmaxf(mx, __shfl_xor(mx, 4));
            mx = fmaxf(mx, __shfl_xor(mx, 8));
            mnew[r]  = fmaxf(m_i[r], mx);
            alpha[r] = __expf(m_i[r] - mnew[r]);
            m_i[r]   = mnew[r];
        }
        float rsum[4] = {0.f, 0.f, 0.f, 0.f};
#pragma unroll
        for (int nt = 0; nt < 4; nt++)
#pragma unroll
            for (int r = 0; r < 4; r++) {
                float p = __expf(S[nt][r] - mnew[r]);
                S[nt][r] = p;
                rsum[r] += p;
            }
#pragma unroll
        for (int r = 0; r < 4; r++) {
            float s = rsum[r];
            s += __shfl_xor(s, 1);
            s += __shfl_xor(s, 2);
            s += __shfl_xor(s, 4);
            s += __shfl_xor(s, 8);
            l_i[r] = l_i[r] * alpha[r] + s;
        }

#pragma unroll
        for (int nt = 0; nt < 4; nt++)
#pragma unroll
            for (int r = 0; r < 4; r++)
                Ps[w][quad * 4 + r][nt * 16 + n] = (__bf16)S[nt][r];

#pragma unroll
        for (int dt = 0; dt < 8; dt++)
#pragma unroll
            for (int r = 0; r < 4; r++) O[dt][r] *= alpha[r];

        bf16x8 pa0 = *(const bf16x8*)&Ps[w][n][quad * 8];
        bf16x8 pa1 = *(const bf16x8*)&Ps[w][n][32 + quad * 8];
#pragma unroll
        for (int dt = 0; dt < 8; dt++) {
            f32x4 acc = O[dt];
            acc = MFMA16(pa0, *(const bf16x8*)&Vs[dt * 16 + n][quad * 8], acc);
            acc = MFMA16(pa1, *(const bf16x8*)&Vs[dt * 16 + n][32 + quad * 8], acc);
            O[dt] = acc;
        }
        __syncthreads();
    }

    float inv[4];
#pragma unroll
    for (int r = 0; r < 4; r++) inv[r] = 1.0f / l_i[r];
#pragma unroll
    for (int dt = 0; dt < 8; dt++)
#pragma unroll
        for (int r = 0; r < 4; r++)
            ob[(long)(qbase + quad * 4 + r) * 4096 + h * 128 + dt * 16 + n] =
                (__bf16)(O[dt][r] * inv[r]);
}

// ---------------------------------------------------------------------------
extern "C" void kernel_launch(void* const* d_in, const int* in_sizes, int n_in,
                              void* d_out, int out_size, void* d_ws, size_t ws_size,
                              hipStream_t stream) {
    const float* hidden = (const float*)d_in[0];
    const float* target = (const float*)d_in[1];
    const float* cosb   = (const float*)d_in[2];
    const float* sinb   = (const float*)d_in[3];
    const float* wq = (const float*)d_in[5];
    const float* wk = (const float*)d_in[6];
    const float* wv = (const float*)d_in[7];
    const float* wo = (const float*)d_in[8];
    const float* qw = (const float*)d_in[9];
    const float* kw = (const float*)d_in[10];
    float* out = (float*)d_out;

    // workspace layout (peak 40 MB, proven safe in R0):
    char* ws = (char*)d_ws;
    __bf16* qbf  = (__bf16*)(ws);                 // 8 MB  [1024][4096], attn out in-place
    __bf16* kbf  = (__bf16*)(ws + (8ll  << 20));  // 6 MB  [3072][1024]
    __bf16* vbf  = (__bf16*)(ws + (14ll << 20));  // 6 MB  [3072][1024]
    __bf16* xcat = (__bf16*)(ws + (20ll << 20));  // 12 MB [3072][2048]; dead after v GEMM
    __bf16* vtg  = (__bf16*)(ws + (20ll << 20));  // 6 MB  [8][128][3072], overlays xcat
    __bf16* wb   = (__bf16*)(ws + (32ll << 20));  // 8 MB  rotating weight buffer

    dim3 blk(256);
    const int CG = 1024;  // conv grid

    // activations -> bf16 (xcat = [target; hidden])
    conv_f32_bf16<<<CG, blk, 0, stream>>>(target, xcat, (2048 * 2048) / 4);
    conv_f32_bf16<<<CG, blk, 0, stream>>>(hidden, xcat + 2048ll * 2048, (1024 * 2048) / 4);

    // q projection in two N-halves through rotating wb
    conv_f32_bf16<<<CG, blk, 0, stream>>>(wq, wb, (2048 * 2048) / 4);
    gemm_bt_mfma<__bf16><<<dim3(16, 8), blk, 0, stream>>>(
        xcat + 2048ll * 2048, wb, qbf, 1024, 2048, 2048, 2048, 2048, 4096);
    conv_f32_bf16<<<CG, blk, 0, stream>>>(wq + 2048ll * 2048, wb, (2048 * 2048) / 4);
    gemm_bt_mfma<__bf16><<<dim3(16, 8), blk, 0, stream>>>(
        xcat + 2048ll * 2048, wb, qbf + 2048, 1024, 2048, 2048, 2048, 2048, 4096);

    // k projection
    conv_f32_bf16<<<CG, blk, 0, stream>>>(wk, wb, (1024 * 2048) / 4);
    gemm_bt_mfma<__bf16><<<dim3(8, 24), blk, 0, stream>>>(
        xcat, wb, kbf, 3072, 1024, 2048, 2048, 2048, 1024);

    // v projection
    conv_f32_bf16<<<CG, blk, 0, stream>>>(wv, wb, (1024 * 2048) / 4);
    gemm_bt_mfma<__bf16><<<dim3(8, 24), blk, 0, stream>>>(
        xcat, wb, vbf, 3072, 1024, 2048, 2048, 2048, 1024);

    // RMSNorm + RoPE in place (q gets the 1/sqrt(HD) fold)
    rmsnorm_rope_bf16<<<(1024 * 32) / 4, blk, 0, stream>>>(
        qbf, qw, cosb, sinb, 32, 4096, 2048, 0.08838834764831845f, 1024 * 32);
    rmsnorm_rope_bf16<<<(3072 * 8) / 4, blk, 0, stream>>>(
        kbf, kw, cosb, sinb, 8, 1024, 0, 1.0f, 3072 * 8);

    // V transpose -> [kvh][d][t] (overlays dead xcat)
    transpose_v<<<dim3(48, 2, 8), blk, 0, stream>>>(vbf, vtg);

    // flash attention, bf16 out in place over qbf
    flash_attn_mfma<<<dim3(512), blk, 0, stream>>>(qbf, kbf, vtg, qbf);

    // output projection in two N-halves through rotating wb
    conv_f32_bf16<<<CG, blk, 0, stream>>>(wo, wb, (1024 * 4096) / 4);
    gemm_bt_mfma<float><<<dim3(8, 8), blk, 0, stream>>>(
        qbf, wb, out, 1024, 1024, 4096, 4096, 4096, 2048);
    conv_f32_bf16<<<CG, blk, 0, stream>>>(wo + 1024ll * 4096, wb, (1024 * 4096) / 4);
    gemm_bt_mfma<float><<<dim3(8, 8), blk, 0, stream>>>(
        qbf, wb, out + 1024, 1024, 1024, 4096, 4096, 4096, 2048);
}

// Round 4
// 477.701 us; speedup vs baseline: 6.7479x; 1.4854x over previous
//
#include <hip/hip_runtime.h>

#define HIDDEN 2048
#define NQ     1024
#define NCTX   2048
#define NTOT   3072
#define NHEADS 32
#define KVH    8
#define HD     128

typedef __attribute__((ext_vector_type(8))) __bf16 bf16x8;
typedef __attribute__((ext_vector_type(4))) __bf16 bf16x4;
typedef __attribute__((ext_vector_type(4))) float  f32x4;

#define MFMA16(a, b, c) __builtin_amdgcn_mfma_f32_16x16x32_bf16(a, b, c, 0, 0, 0)

__device__ __forceinline__ void load_lds16(const void* g, void* l) {
    __builtin_amdgcn_global_load_lds(
        (const __attribute__((address_space(1))) unsigned int*)g,
        (__attribute__((address_space(3))) unsigned int*)l, 16, 0, 0);
}

// ---------------------------------------------------------------------------
// z-fused fp32 -> bf16 convert (two independent jobs per launch)
// ---------------------------------------------------------------------------
__global__ __launch_bounds__(256) void conv2_f32_bf16(const float* __restrict__ s0,
                                                      __bf16* __restrict__ d0, int n0,
                                                      const float* __restrict__ s1,
                                                      __bf16* __restrict__ d1, int n1) {
    const float* s = blockIdx.y ? s1 : s0;
    __bf16*      d = blockIdx.y ? d1 : d0;
    int          n = blockIdx.y ? n1 : n0;
    int i = blockIdx.x * 256 + threadIdx.x;
    int stride = gridDim.x * 256;
    for (; i < n; i += stride) {
        float4 v = ((const float4*)s)[i];
        bf16x4 o;
        o[0] = (__bf16)v.x; o[1] = (__bf16)v.y;
        o[2] = (__bf16)v.z; o[3] = (__bf16)v.w;
        ((bf16x4*)d)[i] = o;
    }
}

__global__ __launch_bounds__(256) void conv_f32_bf16(const float* __restrict__ src,
                                                     __bf16* __restrict__ dst, int n4) {
    int i = blockIdx.x * 256 + threadIdx.x;
    int stride = gridDim.x * 256;
    for (; i < n4; i += stride) {
        float4 v = ((const float4*)src)[i];
        bf16x4 o;
        o[0] = (__bf16)v.x; o[1] = (__bf16)v.y;
        o[2] = (__bf16)v.z; o[3] = (__bf16)v.w;
        ((bf16x4*)dst)[i] = o;
    }
}

// ---------------------------------------------------------------------------
// 128x128 MFMA GEMM tile body (m97 structure), shared by all GEMM kernels.
// Ablk/Bblk/Cblk pre-offset to the tile origin.
// ---------------------------------------------------------------------------
template <typename OutT>
__device__ __forceinline__ void gemm128_body(const __bf16* __restrict__ Ablk,
                                             const __bf16* __restrict__ Bblk,
                                             OutT* __restrict__ Cblk,
                                             int K, int lda, int ldb, int ldc) {
    __shared__ __bf16 As[128][64];
    __shared__ __bf16 Bs[128][64];

    const int tid  = threadIdx.x;
    const int lane = tid & 63;
    const int w    = tid >> 6;
    const int n16  = lane & 15;
    const int quad = lane >> 4;
    const int wm = (w & 1) * 64;
    const int wn = (w >> 1) * 64;

    f32x4 acc[4][4];
    const f32x4 fzero = {0.f, 0.f, 0.f, 0.f};
#pragma unroll
    for (int i = 0; i < 4; i++)
#pragma unroll
        for (int j = 0; j < 4; j++) acc[i][j] = fzero;

    const int srow = w * 32 + (lane >> 3);
    const int scol = (lane & 7) * 8;

    for (int k0 = 0; k0 < K; k0 += 64) {
#pragma unroll
        for (int i = 0; i < 4; i++) {
            int r = srow + i * 8;
            load_lds16(Ablk + (long)r * lda + k0 + scol, &As[r][scol]);
            load_lds16(Bblk + (long)r * ldb + k0 + scol, &Bs[r][scol]);
        }
        __syncthreads();
#pragma unroll
        for (int ks = 0; ks < 2; ks++) {
            bf16x8 af[4], bfr[4];
#pragma unroll
            for (int i = 0; i < 4; i++)
                af[i] = *(const bf16x8*)&As[wm + i * 16 + n16][ks * 32 + quad * 8];
#pragma unroll
            for (int j = 0; j < 4; j++)
                bfr[j] = *(const bf16x8*)&Bs[wn + j * 16 + n16][ks * 32 + quad * 8];
#pragma unroll
            for (int i = 0; i < 4; i++)
#pragma unroll
                for (int j = 0; j < 4; j++)
                    acc[i][j] = MFMA16(af[i], bfr[j], acc[i][j]);
        }
        __syncthreads();
    }

#pragma unroll
    for (int i = 0; i < 4; i++)
#pragma unroll
        for (int j = 0; j < 4; j++)
#pragma unroll
            for (int r = 0; r < 4; r++)
                Cblk[(long)(wm + i * 16 + quad * 4 + r) * ldc + wn + j * 16 + n16] =
                    (OutT)acc[i][j][r];
}

template <typename OutT>
__global__ __launch_bounds__(256) void gemm_bt_mfma(const __bf16* __restrict__ A,
                                                    const __bf16* __restrict__ B,
                                                    OutT* __restrict__ C,
                                                    int K, int lda, int ldb, int ldc) {
    const int m0 = blockIdx.y * 128;
    const int n0 = blockIdx.x * 128;
    gemm128_body<OutT>(A + (long)m0 * lda, B + (long)n0 * ldb,
                       C + (long)m0 * ldc + n0, K, lda, ldb, ldc);
}

// Fused K & V projection: z selects weight/output; m-tiles span [target; hidden].
__global__ __launch_bounds__(256) void gemm_kv(const __bf16* __restrict__ At,
                                               const __bf16* __restrict__ Ah,
                                               const __bf16* __restrict__ Bk,
                                               const __bf16* __restrict__ Bv,
                                               __bf16* __restrict__ Ck,
                                               __bf16* __restrict__ Cv) {
    const int m0 = blockIdx.y * 128;
    const int n0 = blockIdx.x * 128;
    const __bf16* Ablk = (m0 < 2048) ? At + (long)m0 * 2048
                                     : Ah + (long)(m0 - 2048) * 2048;
    const __bf16* B = blockIdx.z ? Bv : Bk;
    __bf16*       C = blockIdx.z ? Cv : Ck;
    gemm128_body<__bf16>(Ablk, B + (long)n0 * 2048, C + (long)m0 * 1024 + n0,
                         2048, 2048, 2048, 1024);
}

// ---------------------------------------------------------------------------
// Fused RMSNorm+RoPE for q (z=0) and k (z=1), in place.
// ---------------------------------------------------------------------------
__global__ __launch_bounds__(256) void rmsnorm_rope2(__bf16* __restrict__ xq,
                                                     const float* __restrict__ wq,
                                                     __bf16* __restrict__ xk,
                                                     const float* __restrict__ wk,
                                                     const float* __restrict__ cosb,
                                                     const float* __restrict__ sinb) {
    const int z = blockIdx.y;
    __bf16*      x = z ? xk : xq;
    const float* w = z ? wk : wq;
    const int nheads     = z ? 8 : 32;
    const int row_stride = z ? 1024 : 4096;
    const int pos_offset = z ? 0 : 2048;
    const float outscale = z ? 1.0f : 0.08838834764831845f;
    const int nitems     = z ? 3072 * 8 : 1024 * 32;

    int item = blockIdx.x * 4 + (threadIdx.x >> 6);
    int lane = threadIdx.x & 63;
    if (item >= nitems) return;
    int row = item / nheads;
    int head = item - row * nheads;
    __bf16* p = x + (long)row * row_stride + head * HD;

    float x1 = (float)p[lane], x2 = (float)p[lane + 64];
    float ss = x1 * x1 + x2 * x2;
#pragma unroll
    for (int o = 32; o >= 1; o >>= 1) ss += __shfl_xor(ss, o);
    float r = rsqrtf(ss * (1.0f / 128.0f) + 1e-6f) * outscale;

    int pos = pos_offset + row;
    float c1 = cosb[pos * HD + lane], c2 = cosb[pos * HD + lane + 64];
    float s1 = sinb[pos * HD + lane], s2 = sinb[pos * HD + lane + 64];
    float y1 = x1 * r * w[lane];
    float y2 = x2 * r * w[lane + 64];
    p[lane]      = (__bf16)(y1 * c1 - y2 * s1);
    p[lane + 64] = (__bf16)(y2 * c2 + y1 * s2);
}

// ---------------------------------------------------------------------------
// V transpose: vbf[t][g*128+d] -> vt[g][d][t]
// ---------------------------------------------------------------------------
__global__ __launch_bounds__(256) void transpose_v(const __bf16* __restrict__ v,
                                                   __bf16* __restrict__ vt) {
    __shared__ __bf16 T[64][68];
    const int tid = threadIdx.x;
    const int t0 = blockIdx.x * 64;
    const int d0 = blockIdx.y * 64;
    const int g  = blockIdx.z;
    const __bf16* src = v + (long)t0 * 1024 + g * 128 + d0;
#pragma unroll
    for (int i = 0; i < 4; i++) {
        int idx = tid + i * 256;
        int r = idx >> 4, c4 = (idx & 15) * 4;
        *(bf16x4*)&T[r][c4] = *(const bf16x4*)(src + (long)r * 1024 + c4);
    }
    __syncthreads();
    __bf16* dst = vt + (long)g * 128 * 3072 + (long)d0 * 3072 + t0;
#pragma unroll
    for (int i = 0; i < 4; i++) {
        int idx = tid + i * 256;
        int r = idx >> 4, c4 = (idx & 15) * 4;
        bf16x4 o;
        o[0] = T[c4 + 0][r]; o[1] = T[c4 + 1][r];
        o[2] = T[c4 + 2][r]; o[3] = T[c4 + 3][r];
        *(bf16x4*)(dst + (long)r * 3072 + c4) = o;
    }
}

// ---------------------------------------------------------------------------
// Split-K MFMA flash attention. Block = (head, 64 q rows, split s of keys).
// Stores raw (unnormalized) bf16 partial O + per-row (m,l) for the merge.
// P-scratch aliases the Ks region (extra barrier guards the reuse).
// ---------------------------------------------------------------------------
__global__ __launch_bounds__(256) void flash_attn_splitk(const __bf16* __restrict__ qb,
                                                         const __bf16* __restrict__ kb,
                                                         const __bf16* __restrict__ vtg,
                                                         __bf16* __restrict__ Opart0,
                                                         __bf16* __restrict__ Opart1,
                                                         float2* __restrict__ ml) {
    __shared__ __bf16 KsU[64 * 136];   // Ks[t][d], stride 136; Ps aliased inside
    __shared__ __bf16 Vs[128][72];     // [d][t]
#define KS(r, c) KsU[(r) * 136 + (c)]
#define PS(w_, m_, t_) KsU[(w_) * (16 * 72) + (m_) * 72 + (t_)]

    const int tid  = threadIdx.x;
    const int lane = tid & 63;
    const int w    = tid >> 6;
    const int n    = lane & 15;
    const int quad = lane >> 4;

    const int bid = blockIdx.x;
    const int s   = blockIdx.y;
    const int g  = bid & 7;
    const int jj = bid >> 3;
    const int h  = g * 4 + (jj & 3);
    const int qt = jj >> 2;

    const int qbase = qt * 64 + w * 16;

    bf16x8 qf[4];
    {
        const __bf16* qp = qb + (long)(qbase + n) * 4096 + h * 128 + quad * 8;
        qf[0] = *(const bf16x8*)(qp);
        qf[1] = *(const bf16x8*)(qp + 32);
        qf[2] = *(const bf16x8*)(qp + 64);
        qf[3] = *(const bf16x8*)(qp + 96);
    }

    f32x4 O[8];
    const f32x4 fzero = {0.f, 0.f, 0.f, 0.f};
#pragma unroll
    for (int dt = 0; dt < 8; dt++) O[dt] = fzero;
    float m_i[4], l_i[4];
#pragma unroll
    for (int r = 0; r < 4; r++) { m_i[r] = -1e30f; l_i[r] = 0.f; }

    const __bf16* Kg = kb + g * 128;
    const __bf16* Vg = vtg + (long)g * 128 * 3072;

    const int ntot = 33 + qt;
    const int half = (ntot + 1) >> 1;
    const int tbeg = s ? half : 0;
    const int tend = s ? ntot : half;

    for (int tt = tbeg; tt < tend; tt++) {
        const int t0 = tt * 64;
#pragma unroll
        for (int i = 0; i < 4; i++) {
            int idx = tid + i * 256;
            int rr = idx >> 4, c8 = (idx & 15) * 8;
            *(bf16x8*)&KS(rr, c8) = *(const bf16x8*)(Kg + (long)(t0 + rr) * 1024 + c8);
        }
#pragma unroll
        for (int i = 0; i < 4; i++) {
            int idx = tid + i * 256;
            int rr = idx >> 3, c8 = (idx & 7) * 8;
            *(bf16x8*)&Vs[rr][c8] = *(const bf16x8*)(Vg + (long)rr * 3072 + t0 + c8);
        }
        __syncthreads();

        f32x4 S[4];
#pragma unroll
        for (int nt = 0; nt < 4; nt++) {
            f32x4 acc = fzero;
#pragma unroll
            for (int ks = 0; ks < 4; ks++)
                acc = MFMA16(qf[ks], *(const bf16x8*)&KS(nt * 16 + n, ks * 32 + quad * 8), acc);
            S[nt] = acc;
        }

        if (tt == ntot - 1) {
#pragma unroll
            for (int nt = 0; nt < 4; nt++)
#pragma unroll
                for (int r = 0; r < 4; r++) {
                    int t   = t0 + nt * 16 + n;
                    int lim = 2048 + qbase + quad * 4 + r;
                    if (t > lim) S[nt][r] = -1e30f;
                }
        }

        // all Ks reads done; Ps may now overwrite the Ks region
        __syncthreads();

        float alpha[4], mnew[4];
#pragma unroll
        for (int r = 0; r < 4; r++) {
            float mx = fmaxf(fmaxf(S[0][r], S[1][r]), fmaxf(S[2][r], S[3][r]));
            mx = fmaxf(mx, __shfl_xor(mx, 1));
            mx = fmaxf(mx, __shfl_xor(mx, 2));
            mx = fmaxf(mx, __shfl_xor(mx, 4));
            mx = fmaxf(mx, __shfl_xor(mx, 8));
            mnew[r]  = fmaxf(m_i[r], mx);
            alpha[r] = __expf(m_i[r] - mnew[r]);
            m_i[r]   = mnew[r];
        }
        float rsum[4] = {0.f, 0.f, 0.f, 0.f};
#pragma unroll
        for (int nt = 0; nt < 4; nt++)
#pragma unroll
            for (int r = 0; r < 4; r++) {
                float p = __expf(S[nt][r] - mnew[r]);
                S[nt][r] = p;
                rsum[r] += p;
            }
#pragma unroll
        for (int r = 0; r < 4; r++) {
            float sm = rsum[r];
            sm += __shfl_xor(sm, 1);
            sm += __shfl_xor(sm, 2);
            sm += __shfl_xor(sm, 4);
            sm += __shfl_xor(sm, 8);
            l_i[r] = l_i[r] * alpha[r] + sm;
        }

#pragma unroll
        for (int nt = 0; nt < 4; nt++)
#pragma unroll
            for (int r = 0; r < 4; r++)
                PS(w, quad * 4 + r, nt * 16 + n) = (__bf16)S[nt][r];

#pragma unroll
        for (int dt = 0; dt < 8; dt++)
#pragma unroll
            for (int r = 0; r < 4; r++) O[dt][r] *= alpha[r];

        bf16x8 pa0 = *(const bf16x8*)&PS(w, n, quad * 8);
        bf16x8 pa1 = *(const bf16x8*)&PS(w, n, 32 + quad * 8);
#pragma unroll
        for (int dt = 0; dt < 8; dt++) {
            f32x4 acc = O[dt];
            acc = MFMA16(pa0, *(const bf16x8*)&Vs[dt * 16 + n][quad * 8], acc);
            acc = MFMA16(pa1, *(const bf16x8*)&Vs[dt * 16 + n][32 + quad * 8], acc);
            O[dt] = acc;
        }
        __syncthreads();
    }

    // epilogue: raw partial O (bf16) + per-row (m, l)
    __bf16* Op = s ? Opart1 : Opart0;
    const long tilebase = (long)(h * 16 + qt) * 64 * 128;
#pragma unroll
    for (int dt = 0; dt < 8; dt++)
#pragma unroll
        for (int r = 0; r < 4; r++)
            Op[tilebase + (long)(w * 16 + quad * 4 + r) * 128 + dt * 16 + n] =
                (__bf16)O[dt][r];
    if (n == 0) {
        const int mlbase = (s * 512 + h * 16 + qt) * 64 + w * 16 + quad * 4;
#pragma unroll
        for (int r = 0; r < 4; r++) {
            float2 v; v.x = m_i[r]; v.y = l_i[r];
            ml[mlbase + r] = v;
        }
    }
#undef KS
#undef PS
}

// ---------------------------------------------------------------------------
// Merge the two split-K partials -> normalized bf16 O, written over qbf.
// ---------------------------------------------------------------------------
__global__ __launch_bounds__(256) void flash_merge(const __bf16* __restrict__ O0,
                                                   const __bf16* __restrict__ O1,
                                                   const float2* __restrict__ ml,
                                                   __bf16* __restrict__ ob) {
    const int bx = blockIdx.x;        // (h, qt)
    const int h  = bx >> 4;
    const int qt = bx & 15;
    const int row  = threadIdx.x >> 2;
    const int cseg = (threadIdx.x & 3) * 32;

    float2 a = ml[(long)bx * 64 + row];
    float2 b = ml[(long)(512 + bx) * 64 + row];
    float m  = fmaxf(a.x, b.x);
    float w0 = __expf(a.x - m);
    float w1 = __expf(b.x - m);
    float inv = 1.0f / (w0 * a.y + w1 * b.y);
    w0 *= inv; w1 *= inv;

    const long src = (long)bx * 64 * 128 + (long)row * 128 + cseg;
    __bf16* dst = ob + (long)(qt * 64 + row) * 4096 + h * 128 + cseg;
#pragma unroll
    for (int j = 0; j < 4; j++) {
        bf16x8 x0 = *(const bf16x8*)(O0 + src + j * 8);
        bf16x8 x1 = *(const bf16x8*)(O1 + src + j * 8);
        bf16x8 o;
#pragma unroll
        for (int k = 0; k < 8; k++)
            o[k] = (__bf16)(w0 * (float)x0[k] + w1 * (float)x1[k]);
        *(bf16x8*)(dst + j * 8) = o;
    }
}

// ---------------------------------------------------------------------------
extern "C" void kernel_launch(void* const* d_in, const int* in_sizes, int n_in,
                              void* d_out, int out_size, void* d_ws, size_t ws_size,
                              hipStream_t stream) {
    const float* hidden = (const float*)d_in[0];
    const float* target = (const float*)d_in[1];
    const float* cosb   = (const float*)d_in[2];
    const float* sinb   = (const float*)d_in[3];
    const float* wq = (const float*)d_in[5];
    const float* wk = (const float*)d_in[6];
    const float* wv = (const float*)d_in[7];
    const float* wo = (const float*)d_in[8];
    const float* qw = (const float*)d_in[9];
    const float* kw = (const float*)d_in[10];
    float* out = (float*)d_out;

    // 40 MB workspace map (phased overlays; stream order guarantees safety):
    char* ws = (char*)d_ws;
    const long MB = 1 << 20;
    __bf16* qbf  = (__bf16*)(ws);             // @0..8   q / attn out
    __bf16* kbf  = (__bf16*)(ws + 8 * MB);    // @8..14  k
    __bf16* vbf  = (__bf16*)(ws + 14 * MB);   // @14..20 v (dead after transpose)
    __bf16* hidb = (__bf16*)(ws + 20 * MB);   // @20..24 hidden bf16 (dead after q gemm)
    __bf16* tgtb = (__bf16*)(ws + 24 * MB);   // @24..32 target bf16 (dead after kv gemm)
    __bf16* wkb  = (__bf16*)(ws + 32 * MB);   // @32..36
    __bf16* wvb  = (__bf16*)(ws + 36 * MB);   // @36..40
    __bf16* wqb  = (__bf16*)(ws + 24 * MB);   // @24..40 (16 MB, after tgtb/wkb/wvb die)
    __bf16* vtg  = (__bf16*)(ws + 24 * MB);   // @24..30 (after wqb dies)
    __bf16* Op0  = (__bf16*)(ws + 14 * MB);   // @14..22 split-0 partial (vbf+hidb dead)
    __bf16* Op1  = (__bf16*)(ws + 30 * MB);   // @30..38 split-1 partial
    float2* mlb  = (float2*)(ws + 38 * MB);   // @38..38.5
    __bf16* wob  = (__bf16*)(ws + 24 * MB);   // @24..40 (after flash+merge)

    dim3 blk(256);

    // activations + k/v weights -> bf16 (2 fused launches)
    conv2_f32_bf16<<<dim3(1024, 2), blk, 0, stream>>>(
        target, tgtb, (2048 * 2048) / 4, hidden, hidb, (1024 * 2048) / 4);
    conv2_f32_bf16<<<dim3(1024, 2), blk, 0, stream>>>(
        wk, wkb, (1024 * 2048) / 4, wv, wvb, (1024 * 2048) / 4);

    // fused k & v projections: one launch, 384 blocks
    gemm_kv<<<dim3(8, 24, 2), blk, 0, stream>>>(tgtb, hidb, wkb, wvb, kbf, vbf);

    // q projection: single 256-block launch
    conv_f32_bf16<<<2048, blk, 0, stream>>>(wq, wqb, (4096 * 2048) / 4);
    gemm_bt_mfma<__bf16><<<dim3(32, 8), blk, 0, stream>>>(
        hidb, wqb, qbf, 2048, 2048, 2048, 4096);

    // fused RMSNorm + RoPE (q and k)
    rmsnorm_rope2<<<dim3(8192, 2), blk, 0, stream>>>(qbf, qw, kbf, kw, cosb, sinb);

    // V transpose -> [g][d][t]
    transpose_v<<<dim3(48, 2, 8), blk, 0, stream>>>(vbf, vtg);

    // split-K flash attention (1024 blocks) + merge
    flash_attn_splitk<<<dim3(512, 2), blk, 0, stream>>>(qbf, kbf, vtg, Op0, Op1, mlb);
    flash_merge<<<512, blk, 0, stream>>>(Op0, Op1, mlb, qbf);

    // output projection
    conv_f32_bf16<<<2048, blk, 0, stream>>>(wo, wob, (2048 * 4096) / 4);
    gemm_bt_mfma<float><<<dim3(16, 8), blk, 0, stream>>>(
        qbf, wob, out, 4096, 4096, 4096, 2048);
}

// Round 5
// 418.979 us; speedup vs baseline: 7.6936x; 1.1402x over previous
//
#include <hip/hip_runtime.h>

#define HIDDEN 2048
#define NQ     1024
#define NCTX   2048
#define NTOT   3072
#define NHEADS 32
#define KVH    8
#define HD     128

typedef __attribute__((ext_vector_type(8))) __bf16 bf16x8;
typedef __attribute__((ext_vector_type(4))) __bf16 bf16x4;
typedef __attribute__((ext_vector_type(4))) float  f32x4;

#define MFMA16(a, b, c) __builtin_amdgcn_mfma_f32_16x16x32_bf16(a, b, c, 0, 0, 0)

// Fixed softmax shift: scores are bounded by Cauchy-Schwarz —
// |q|=1 (rmsnorm w/ folded 1/sqrt(d)), |k|=sqrt(128)=11.31, RoPE preserves
// norms, so s <= 11.4 incl. bf16 rounding. exp(s-12) in [3.8e-11, 1].
#define MSTATIC 12.0f

__device__ __forceinline__ void load_lds16(const void* g, void* l) {
    __builtin_amdgcn_global_load_lds(
        (const __attribute__((address_space(1))) unsigned int*)g,
        (__attribute__((address_space(3))) unsigned int*)l, 16, 0, 0);
}

// ---------------------------------------------------------------------------
// 4-way fused fp32 -> bf16 convert
// ---------------------------------------------------------------------------
__global__ __launch_bounds__(256) void conv4_f32_bf16(const float* __restrict__ s0,
                                                      __bf16* __restrict__ d0, int n0,
                                                      const float* __restrict__ s1,
                                                      __bf16* __restrict__ d1, int n1,
                                                      const float* __restrict__ s2,
                                                      __bf16* __restrict__ d2, int n2,
                                                      const float* __restrict__ s3,
                                                      __bf16* __restrict__ d3, int n3) {
    const float* s; __bf16* d; int n;
    switch (blockIdx.y) {
        case 0: s = s0; d = d0; n = n0; break;
        case 1: s = s1; d = d1; n = n1; break;
        case 2: s = s2; d = d2; n = n2; break;
        default: s = s3; d = d3; n = n3; break;
    }
    int i = blockIdx.x * 256 + threadIdx.x;
    int stride = gridDim.x * 256;
    for (; i < n; i += stride) {
        float4 v = ((const float4*)s)[i];
        bf16x4 o;
        o[0] = (__bf16)v.x; o[1] = (__bf16)v.y;
        o[2] = (__bf16)v.z; o[3] = (__bf16)v.w;
        ((bf16x4*)d)[i] = o;
    }
}

__global__ __launch_bounds__(256) void conv_f32_bf16(const float* __restrict__ src,
                                                     __bf16* __restrict__ dst, int n4) {
    int i = blockIdx.x * 256 + threadIdx.x;
    int stride = gridDim.x * 256;
    for (; i < n4; i += stride) {
        float4 v = ((const float4*)src)[i];
        bf16x4 o;
        o[0] = (__bf16)v.x; o[1] = (__bf16)v.y;
        o[2] = (__bf16)v.z; o[3] = (__bf16)v.w;
        ((bf16x4*)dst)[i] = o;
    }
}

// ---------------------------------------------------------------------------
// 128x128 MFMA GEMM tile body (m97 structure)
// ---------------------------------------------------------------------------
template <typename OutT>
__device__ __forceinline__ void gemm128_body(const __bf16* __restrict__ Ablk,
                                             const __bf16* __restrict__ Bblk,
                                             OutT* __restrict__ Cblk,
                                             int K, int lda, int ldb, int ldc) {
    __shared__ __bf16 As[128][64];
    __shared__ __bf16 Bs[128][64];

    const int tid  = threadIdx.x;
    const int lane = tid & 63;
    const int w    = tid >> 6;
    const int n16  = lane & 15;
    const int quad = lane >> 4;
    const int wm = (w & 1) * 64;
    const int wn = (w >> 1) * 64;

    f32x4 acc[4][4];
    const f32x4 fzero = {0.f, 0.f, 0.f, 0.f};
#pragma unroll
    for (int i = 0; i < 4; i++)
#pragma unroll
        for (int j = 0; j < 4; j++) acc[i][j] = fzero;

    const int srow = w * 32 + (lane >> 3);
    const int scol = (lane & 7) * 8;

    for (int k0 = 0; k0 < K; k0 += 64) {
#pragma unroll
        for (int i = 0; i < 4; i++) {
            int r = srow + i * 8;
            load_lds16(Ablk + (long)r * lda + k0 + scol, &As[r][scol]);
            load_lds16(Bblk + (long)r * ldb + k0 + scol, &Bs[r][scol]);
        }
        __syncthreads();
#pragma unroll
        for (int ks = 0; ks < 2; ks++) {
            bf16x8 af[4], bfr[4];
#pragma unroll
            for (int i = 0; i < 4; i++)
                af[i] = *(const bf16x8*)&As[wm + i * 16 + n16][ks * 32 + quad * 8];
#pragma unroll
            for (int j = 0; j < 4; j++)
                bfr[j] = *(const bf16x8*)&Bs[wn + j * 16 + n16][ks * 32 + quad * 8];
#pragma unroll
            for (int i = 0; i < 4; i++)
#pragma unroll
                for (int j = 0; j < 4; j++)
                    acc[i][j] = MFMA16(af[i], bfr[j], acc[i][j]);
        }
        __syncthreads();
    }

#pragma unroll
    for (int i = 0; i < 4; i++)
#pragma unroll
        for (int j = 0; j < 4; j++)
#pragma unroll
            for (int r = 0; r < 4; r++)
                Cblk[(long)(wm + i * 16 + quad * 4 + r) * ldc + wn + j * 16 + n16] =
                    (OutT)acc[i][j][r];
}

template <typename OutT>
__global__ __launch_bounds__(256) void gemm_bt_mfma(const __bf16* __restrict__ A,
                                                    const __bf16* __restrict__ B,
                                                    OutT* __restrict__ C,
                                                    int K, int lda, int ldb, int ldc) {
    const int m0 = blockIdx.y * 128;
    const int n0 = blockIdx.x * 128;
    gemm128_body<OutT>(A + (long)m0 * lda, B + (long)n0 * ldb,
                       C + (long)m0 * ldc + n0, K, lda, ldb, ldc);
}

// Split-K GEMM: z picks K-half and partial output buffer (f32).
__global__ __launch_bounds__(256) void gemm_bt_splitk(const __bf16* __restrict__ A,
                                                      const __bf16* __restrict__ B,
                                                      float* __restrict__ C0,
                                                      float* __restrict__ C1,
                                                      int Khalf, int lda, int ldb, int ldc) {
    const int m0 = blockIdx.y * 128;
    const int n0 = blockIdx.x * 128;
    const int koff = blockIdx.z * Khalf;
    float* C = blockIdx.z ? C1 : C0;
    gemm128_body<float>(A + (long)m0 * lda + koff, B + (long)n0 * ldb + koff,
                        C + (long)m0 * ldc + n0, Khalf, lda, ldb, ldc);
}

__global__ __launch_bounds__(256) void add_halves(const float* __restrict__ p0,
                                                  const float* __restrict__ p1,
                                                  float* __restrict__ out, int n4) {
    int i = blockIdx.x * 256 + threadIdx.x;
    int stride = gridDim.x * 256;
    for (; i < n4; i += stride) {
        float4 a = ((const float4*)p0)[i];
        float4 b = ((const float4*)p1)[i];
        float4 o; o.x = a.x + b.x; o.y = a.y + b.y; o.z = a.z + b.z; o.w = a.w + b.w;
        ((float4*)out)[i] = o;
    }
}

// Fused K & V projection
__global__ __launch_bounds__(256) void gemm_kv(const __bf16* __restrict__ At,
                                               const __bf16* __restrict__ Ah,
                                               const __bf16* __restrict__ Bk,
                                               const __bf16* __restrict__ Bv,
                                               __bf16* __restrict__ Ck,
                                               __bf16* __restrict__ Cv) {
    const int m0 = blockIdx.y * 128;
    const int n0 = blockIdx.x * 128;
    const __bf16* Ablk = (m0 < 2048) ? At + (long)m0 * 2048
                                     : Ah + (long)(m0 - 2048) * 2048;
    const __bf16* B = blockIdx.z ? Bv : Bk;
    __bf16*       C = blockIdx.z ? Cv : Ck;
    gemm128_body<__bf16>(Ablk, B + (long)n0 * 2048, C + (long)m0 * 1024 + n0,
                         2048, 2048, 2048, 1024);
}

// ---------------------------------------------------------------------------
// Fused RMSNorm+RoPE for q (z=0) and k (z=1), in place.
// ---------------------------------------------------------------------------
__global__ __launch_bounds__(256) void rmsnorm_rope2(__bf16* __restrict__ xq,
                                                     const float* __restrict__ wq,
                                                     __bf16* __restrict__ xk,
                                                     const float* __restrict__ wk,
                                                     const float* __restrict__ cosb,
                                                     const float* __restrict__ sinb) {
    const int z = blockIdx.y;
    __bf16*      x = z ? xk : xq;
    const float* w = z ? wk : wq;
    const int nheads     = z ? 8 : 32;
    const int row_stride = z ? 1024 : 4096;
    const int pos_offset = z ? 0 : 2048;
    const float outscale = z ? 1.0f : 0.08838834764831845f;
    const int nitems     = z ? 3072 * 8 : 1024 * 32;

    int item = blockIdx.x * 4 + (threadIdx.x >> 6);
    int lane = threadIdx.x & 63;
    if (item >= nitems) return;
    int row = item / nheads;
    int head = item - row * nheads;
    __bf16* p = x + (long)row * row_stride + head * HD;

    float x1 = (float)p[lane], x2 = (float)p[lane + 64];
    float ss = x1 * x1 + x2 * x2;
#pragma unroll
    for (int o = 32; o >= 1; o >>= 1) ss += __shfl_xor(ss, o);
    float r = rsqrtf(ss * (1.0f / 128.0f) + 1e-6f) * outscale;

    int pos = pos_offset + row;
    float c1 = cosb[pos * HD + lane], c2 = cosb[pos * HD + lane + 64];
    float s1 = sinb[pos * HD + lane], s2 = sinb[pos * HD + lane + 64];
    float y1 = x1 * r * w[lane];
    float y2 = x2 * r * w[lane + 64];
    p[lane]      = (__bf16)(y1 * c1 - y2 * s1);
    p[lane + 64] = (__bf16)(y2 * c2 + y1 * s2);
}

// ---------------------------------------------------------------------------
// V transpose: vbf[t][g*128+d] -> vt[g][d][t]
// ---------------------------------------------------------------------------
__global__ __launch_bounds__(256) void transpose_v(const __bf16* __restrict__ v,
                                                   __bf16* __restrict__ vt) {
    __shared__ __bf16 T[64][68];
    const int tid = threadIdx.x;
    const int t0 = blockIdx.x * 64;
    const int d0 = blockIdx.y * 64;
    const int g  = blockIdx.z;
    const __bf16* src = v + (long)t0 * 1024 + g * 128 + d0;
#pragma unroll
    for (int i = 0; i < 4; i++) {
        int idx = tid + i * 256;
        int r = idx >> 4, c4 = (idx & 15) * 4;
        *(bf16x4*)&T[r][c4] = *(const bf16x4*)(src + (long)r * 1024 + c4);
    }
    __syncthreads();
    __bf16* dst = vt + (long)g * 128 * 3072 + (long)d0 * 3072 + t0;
#pragma unroll
    for (int i = 0; i < 4; i++) {
        int idx = tid + i * 256;
        int r = idx >> 4, c4 = (idx & 15) * 4;
        bf16x4 o;
        o[0] = T[c4 + 0][r]; o[1] = T[c4 + 1][r];
        o[2] = T[c4 + 2][r]; o[3] = T[c4 + 3][r];
        *(bf16x4*)(dst + (long)r * 3072 + c4) = o;
    }
}

// ---------------------------------------------------------------------------
// Split-K flash attention with FIXED softmax shift (m = MSTATIC).
// No running max, no alpha rescale, no per-tile reductions; row-sums
// accumulate lane-locally and reduce once per block. Merge is additive.
// ---------------------------------------------------------------------------
__global__ __launch_bounds__(256) void flash_attn_splitk(const __bf16* __restrict__ qb,
                                                         const __bf16* __restrict__ kb,
                                                         const __bf16* __restrict__ vtg,
                                                         __bf16* __restrict__ Opart0,
                                                         __bf16* __restrict__ Opart1,
                                                         float* __restrict__ lsum) {
    __shared__ __bf16 KsU[64 * 136];   // Ks[t][d] stride 136; Ps aliased inside
    __shared__ __bf16 Vs[128][72];     // [d][t]
#define KS(r, c) KsU[(r) * 136 + (c)]
#define PS(w_, m_, t_) KsU[(w_) * (16 * 72) + (m_) * 72 + (t_)]

    const int tid  = threadIdx.x;
    const int lane = tid & 63;
    const int w    = tid >> 6;
    const int n    = lane & 15;
    const int quad = lane >> 4;

    const int bid = blockIdx.x;
    const int s   = blockIdx.y;
    const int g  = bid & 7;
    const int jj = bid >> 3;
    const int h  = g * 4 + (jj & 3);
    const int qt = jj >> 2;

    const int qbase = qt * 64 + w * 16;

    bf16x8 qf[4];
    {
        const __bf16* qp = qb + (long)(qbase + n) * 4096 + h * 128 + quad * 8;
        qf[0] = *(const bf16x8*)(qp);
        qf[1] = *(const bf16x8*)(qp + 32);
        qf[2] = *(const bf16x8*)(qp + 64);
        qf[3] = *(const bf16x8*)(qp + 96);
    }

    f32x4 O[8];
    const f32x4 fzero = {0.f, 0.f, 0.f, 0.f};
#pragma unroll
    for (int dt = 0; dt < 8; dt++) O[dt] = fzero;
    float l_loc[4] = {0.f, 0.f, 0.f, 0.f};

    const int ntot = 33 + qt;
    const int half = (ntot + 1) >> 1;
    const int tbeg = s ? half : 0;
    const int tend = s ? ntot : half;

    // hoisted staging pointers (incremented per tile)
    const int krr = tid >> 4, kc8 = (tid & 15) * 8;        // K: 64 rows x 128 cols
    const int vrr = tid >> 3, vc8 = (tid & 7) * 8;         // V: 128 rows x 64 cols
    const __bf16* kp = kb + g * 128 + (long)(tbeg * 64 + krr) * 1024 + kc8;
    const __bf16* vp = vtg + (long)g * 128 * 3072 + (long)vrr * 3072 + tbeg * 64 + vc8;

    for (int tt = tbeg; tt < tend; tt++) {
#pragma unroll
        for (int i = 0; i < 4; i++)
            *(bf16x8*)&KS(krr + i * 16, kc8) = *(const bf16x8*)(kp + (long)i * 16 * 1024);
#pragma unroll
        for (int i = 0; i < 4; i++)
            *(bf16x8*)&Vs[vrr + i * 32][vc8] = *(const bf16x8*)(vp + (long)i * 32 * 3072);
        kp += 64 * 1024;
        vp += 64;
        __syncthreads();

        f32x4 S[4];
#pragma unroll
        for (int nt = 0; nt < 4; nt++) {
            f32x4 acc = fzero;
#pragma unroll
            for (int ks = 0; ks < 4; ks++)
                acc = MFMA16(qf[ks], *(const bf16x8*)&KS(nt * 16 + n, ks * 32 + quad * 8), acc);
            S[nt] = acc;
        }

        if (tt == ntot - 1) {
            const int t0 = tt * 64;
#pragma unroll
            for (int nt = 0; nt < 4; nt++)
#pragma unroll
                for (int r = 0; r < 4; r++) {
                    int t   = t0 + nt * 16 + n;
                    int lim = 2048 + qbase + quad * 4 + r;
                    if (t > lim) S[nt][r] = -1e30f;
                }
        }

        // all Ks frag reads done; Ps may overwrite the Ks region
        __syncthreads();

        // fixed-shift softmax: exp only, lane-local row-sum accumulation
#pragma unroll
        for (int nt = 0; nt < 4; nt++)
#pragma unroll
            for (int r = 0; r < 4; r++) {
                float p = __expf(S[nt][r] - MSTATIC);
                S[nt][r] = p;
                l_loc[r] += p;
            }

#pragma unroll
        for (int nt = 0; nt < 4; nt++)
#pragma unroll
            for (int r = 0; r < 4; r++)
                PS(w, quad * 4 + r, nt * 16 + n) = (__bf16)S[nt][r];

        bf16x8 pa0 = *(const bf16x8*)&PS(w, n, quad * 8);
        bf16x8 pa1 = *(const bf16x8*)&PS(w, n, 32 + quad * 8);
#pragma unroll
        for (int dt = 0; dt < 8; dt++) {
            f32x4 acc = O[dt];
            acc = MFMA16(pa0, *(const bf16x8*)&Vs[dt * 16 + n][quad * 8], acc);
            acc = MFMA16(pa1, *(const bf16x8*)&Vs[dt * 16 + n][32 + quad * 8], acc);
            O[dt] = acc;
        }
        __syncthreads();
    }

    // one reduction per block: row sums across the 16 n-lanes
#pragma unroll
    for (int r = 0; r < 4; r++) {
        float sm = l_loc[r];
        sm += __shfl_xor(sm, 1);
        sm += __shfl_xor(sm, 2);
        sm += __shfl_xor(sm, 4);
        sm += __shfl_xor(sm, 8);
        l_loc[r] = sm;
    }

    __bf16* Op = s ? Opart1 : Opart0;
    const long tilebase = (long)(h * 16 + qt) * 64 * 128;
#pragma unroll
    for (int dt = 0; dt < 8; dt++)
#pragma unroll
        for (int r = 0; r < 4; r++)
            Op[tilebase + (long)(w * 16 + quad * 4 + r) * 128 + dt * 16 + n] =
                (__bf16)O[dt][r];
    if (n == 0) {
        const int lbase = (s * 512 + h * 16 + qt) * 64 + w * 16 + quad * 4;
#pragma unroll
        for (int r = 0; r < 4; r++) lsum[lbase + r] = l_loc[r];
    }
#undef KS
#undef PS
}

// ---------------------------------------------------------------------------
// Additive merge of the two split-K partials -> normalized bf16 O over qbf.
// ---------------------------------------------------------------------------
__global__ __launch_bounds__(256) void flash_merge(const __bf16* __restrict__ O0,
                                                   const __bf16* __restrict__ O1,
                                                   const float* __restrict__ lsum,
                                                   __bf16* __restrict__ ob) {
    const int bx = blockIdx.x;        // (h, qt)
    const int h  = bx >> 4;
    const int qt = bx & 15;
    const int row  = threadIdx.x >> 2;
    const int cseg = (threadIdx.x & 3) * 32;

    float inv = 1.0f / (lsum[bx * 64 + row] + lsum[(512 + bx) * 64 + row]);

    const long src = (long)bx * 64 * 128 + (long)row * 128 + cseg;
    __bf16* dst = ob + (long)(qt * 64 + row) * 4096 + h * 128 + cseg;
#pragma unroll
    for (int j = 0; j < 4; j++) {
        bf16x8 x0 = *(const bf16x8*)(O0 + src + j * 8);
        bf16x8 x1 = *(const bf16x8*)(O1 + src + j * 8);
        bf16x8 o;
#pragma unroll
        for (int k = 0; k < 8; k++)
            o[k] = (__bf16)(((float)x0[k] + (float)x1[k]) * inv);
        *(bf16x8*)(dst + j * 8) = o;
    }
}

// ---------------------------------------------------------------------------
extern "C" void kernel_launch(void* const* d_in, const int* in_sizes, int n_in,
                              void* d_out, int out_size, void* d_ws, size_t ws_size,
                              hipStream_t stream) {
    const float* hidden = (const float*)d_in[0];
    const float* target = (const float*)d_in[1];
    const float* cosb   = (const float*)d_in[2];
    const float* sinb   = (const float*)d_in[3];
    const float* wq = (const float*)d_in[5];
    const float* wk = (const float*)d_in[6];
    const float* wv = (const float*)d_in[7];
    const float* wo = (const float*)d_in[8];
    const float* qw = (const float*)d_in[9];
    const float* kw = (const float*)d_in[10];
    float* out = (float*)d_out;

    // 40 MB workspace, phased overlays (stream order guarantees safety):
    char* ws = (char*)d_ws;
    const long MB = 1 << 20;
    __bf16* qbf  = (__bf16*)(ws);             // @0..8   q / attn out
    __bf16* kbf  = (__bf16*)(ws + 8 * MB);    // @8..14  k (dead after flash)
    __bf16* vbf  = (__bf16*)(ws + 14 * MB);   // @14..20 v (dead after transpose)
    __bf16* hidb = (__bf16*)(ws + 20 * MB);   // @20..24 (dead after q gemm)
    __bf16* tgtb = (__bf16*)(ws + 24 * MB);   // @24..32 (dead after kv gemm)
    __bf16* wkb  = (__bf16*)(ws + 32 * MB);   // @32..36
    __bf16* wvb  = (__bf16*)(ws + 36 * MB);   // @36..40
    __bf16* wqb  = (__bf16*)(ws + 24 * MB);   // @24..40 after tgtb/wkb/wvb die
    __bf16* vtg  = (__bf16*)(ws + 24 * MB);   // @24..30 after wqb dies
    __bf16* Op1  = (__bf16*)(ws + 14 * MB);   // @14..22 (vbf+hidb dead)
    __bf16* Op0  = (__bf16*)(ws + 30 * MB);   // @30..38
    float*  lbuf = (float*)(ws + 38 * MB);    // @38..38.25
    __bf16* wob  = (__bf16*)(ws + 8 * MB);    // @8..24 after flash+merge
    float*  po0  = (float*)(ws + 24 * MB);    // @24..32 wo partial 0
    float*  po1  = (float*)(ws + 32 * MB);    // @32..40 wo partial 1

    dim3 blk(256);

    // all pre-GEMM conversions in one launch
    conv4_f32_bf16<<<dim3(512, 4), blk, 0, stream>>>(
        target, tgtb, (2048 * 2048) / 4,
        hidden, hidb, (1024 * 2048) / 4,
        wk, wkb, (1024 * 2048) / 4,
        wv, wvb, (1024 * 2048) / 4);

    // fused k & v projections (384 blocks)
    gemm_kv<<<dim3(8, 24, 2), blk, 0, stream>>>(tgtb, hidb, wkb, wvb, kbf, vbf);

    // q projection (256 blocks)
    conv_f32_bf16<<<2048, blk, 0, stream>>>(wq, wqb, (4096 * 2048) / 4);
    gemm_bt_mfma<__bf16><<<dim3(32, 8), blk, 0, stream>>>(
        hidb, wqb, qbf, 2048, 2048, 2048, 4096);

    // fused RMSNorm + RoPE (q and k)
    rmsnorm_rope2<<<dim3(8192, 2), blk, 0, stream>>>(qbf, qw, kbf, kw, cosb, sinb);

    // V transpose -> [g][d][t]
    transpose_v<<<dim3(48, 2, 8), blk, 0, stream>>>(vbf, vtg);

    // split-K flash attention (1024 blocks) + additive merge
    flash_attn_splitk<<<dim3(512, 2), blk, 0, stream>>>(qbf, kbf, vtg, Op0, Op1, lbuf);
    flash_merge<<<512, blk, 0, stream>>>(Op0, Op1, lbuf, qbf);

    // output projection, split-K (256 blocks) + add
    conv_f32_bf16<<<2048, blk, 0, stream>>>(wo, wob, (2048 * 4096) / 4);
    gemm_bt_splitk<<<dim3(16, 8, 2), blk, 0, stream>>>(
        qbf, wob, po0, po1, 2048, 4096, 4096, 2048);
    add_halves<<<1024, blk, 0, stream>>>(po0, po1, out, (1024 * 2048) / 4);
}

// Round 6
// 398.594 us; speedup vs baseline: 8.0871x; 1.0511x over previous
//
#include <hip/hip_runtime.h>

#define HIDDEN 2048
#define NQ     1024
#define NCTX   2048
#define NTOT   3072
#define NHEADS 32
#define KVH    8
#define HD     128

typedef __attribute__((ext_vector_type(8))) __bf16 bf16x8;
typedef __attribute__((ext_vector_type(4))) __bf16 bf16x4;
typedef __attribute__((ext_vector_type(4))) float  f32x4;

#define MFMA16(a, b, c) __builtin_amdgcn_mfma_f32_16x16x32_bf16(a, b, c, 0, 0, 0)

// Fixed softmax shift (Cauchy-Schwarz: |q|=1 after folded 1/sqrt(d), |k|=sqrt(128),
// RoPE norm-preserving => s <= 11.4 incl. bf16 rounding).
#define MSTATIC 12.0f

__device__ __forceinline__ void load_lds16(const void* g, void* l) {
    __builtin_amdgcn_global_load_lds(
        (const __attribute__((address_space(1))) unsigned int*)g,
        (__attribute__((address_space(3))) unsigned int*)l, 16, 0, 0);
}

// ---------------------------------------------------------------------------
// z-fused fp32 -> bf16 convert (activations only; weights convert in-GEMM)
// ---------------------------------------------------------------------------
__global__ __launch_bounds__(256) void conv2_f32_bf16(const float* __restrict__ s0,
                                                      __bf16* __restrict__ d0, int n0,
                                                      const float* __restrict__ s1,
                                                      __bf16* __restrict__ d1, int n1) {
    const float* s = blockIdx.y ? s1 : s0;
    __bf16*      d = blockIdx.y ? d1 : d0;
    int          n = blockIdx.y ? n1 : n0;
    int i = blockIdx.x * 256 + threadIdx.x;
    int stride = gridDim.x * 256;
    for (; i < n; i += stride) {
        float4 v = ((const float4*)s)[i];
        bf16x4 o;
        o[0] = (__bf16)v.x; o[1] = (__bf16)v.y;
        o[2] = (__bf16)v.z; o[3] = (__bf16)v.w;
        ((bf16x4*)d)[i] = o;
    }
}

// ---------------------------------------------------------------------------
// 128x128 MFMA GEMM tile body; A bf16 (async global->LDS), B fp32
// (register-staged + converted to bf16 in LDS). m97 inner structure.
// ---------------------------------------------------------------------------
template <typename OutT>
__device__ __forceinline__ void gemm128_f32b(const __bf16* __restrict__ Ablk,
                                             const float* __restrict__ Bblk,
                                             OutT* __restrict__ Cblk,
                                             int K, int lda, int ldb, int ldc) {
    __shared__ __bf16 As[128][64];
    __shared__ __bf16 Bs[128][64];

    const int tid  = threadIdx.x;
    const int lane = tid & 63;
    const int w    = tid >> 6;
    const int n16  = lane & 15;
    const int quad = lane >> 4;
    const int wm = (w & 1) * 64;
    const int wn = (w >> 1) * 64;

    f32x4 acc[4][4];
    const f32x4 fzero = {0.f, 0.f, 0.f, 0.f};
#pragma unroll
    for (int i = 0; i < 4; i++)
#pragma unroll
        for (int j = 0; j < 4; j++) acc[i][j] = fzero;

    const int srow = w * 32 + (lane >> 3);
    const int scol = (lane & 7) * 8;

    for (int k0 = 0; k0 < K; k0 += 64) {
        // A: async bf16 staging
#pragma unroll
        for (int i = 0; i < 4; i++) {
            int r = srow + i * 8;
            load_lds16(Ablk + (long)r * lda + k0 + scol, &As[r][scol]);
        }
        // B: fp32 load -> cvt -> LDS bf16
#pragma unroll
        for (int i = 0; i < 4; i++) {
            int id = tid + i * 256;
            int br = id >> 3, c8 = (id & 7) * 8;
            float4 f0 = *(const float4*)(Bblk + (long)br * ldb + k0 + c8);
            float4 f1 = *(const float4*)(Bblk + (long)br * ldb + k0 + c8 + 4);
            bf16x8 bb;
            bb[0] = (__bf16)f0.x; bb[1] = (__bf16)f0.y;
            bb[2] = (__bf16)f0.z; bb[3] = (__bf16)f0.w;
            bb[4] = (__bf16)f1.x; bb[5] = (__bf16)f1.y;
            bb[6] = (__bf16)f1.z; bb[7] = (__bf16)f1.w;
            *(bf16x8*)&Bs[br][c8] = bb;
        }
        __syncthreads();
#pragma unroll
        for (int ks = 0; ks < 2; ks++) {
            bf16x8 af[4], bfr[4];
#pragma unroll
            for (int i = 0; i < 4; i++)
                af[i] = *(const bf16x8*)&As[wm + i * 16 + n16][ks * 32 + quad * 8];
#pragma unroll
            for (int j = 0; j < 4; j++)
                bfr[j] = *(const bf16x8*)&Bs[wn + j * 16 + n16][ks * 32 + quad * 8];
#pragma unroll
            for (int i = 0; i < 4; i++)
#pragma unroll
                for (int j = 0; j < 4; j++)
                    acc[i][j] = MFMA16(af[i], bfr[j], acc[i][j]);
        }
        __syncthreads();
    }

#pragma unroll
    for (int i = 0; i < 4; i++)
#pragma unroll
        for (int j = 0; j < 4; j++)
#pragma unroll
            for (int r = 0; r < 4; r++)
                Cblk[(long)(wm + i * 16 + quad * 4 + r) * ldc + wn + j * 16 + n16] =
                    (OutT)acc[i][j][r];
}

// ---------------------------------------------------------------------------
// Fused k + v + q projections in ONE launch (640 blocks).
// blocks 0..191: k, 192..383: v, 384..639: q.
// ---------------------------------------------------------------------------
__global__ __launch_bounds__(256) void gemm_kvq(const __bf16* __restrict__ tgtb,
                                                const __bf16* __restrict__ hidb,
                                                const float* __restrict__ wk,
                                                const float* __restrict__ wv,
                                                const float* __restrict__ wq,
                                                __bf16* __restrict__ kbf,
                                                __bf16* __restrict__ vbf,
                                                __bf16* __restrict__ qbf) {
    const int b = blockIdx.x;
    const __bf16* Ap; const float* Bp; __bf16* Cp; int ldc;
    if (b < 384) {
        const int z = b / 192, bb = b - z * 192;
        const int n0 = (bb & 7) * 128, m0 = (bb >> 3) * 128;
        Ap = (m0 < 2048) ? tgtb + (long)m0 * 2048 : hidb + (long)(m0 - 2048) * 2048;
        Bp = (z ? wv : wk) + (long)n0 * 2048;
        Cp = (z ? vbf : kbf) + (long)m0 * 1024 + n0;
        ldc = 1024;
    } else {
        const int bb = b - 384;
        const int n0 = (bb & 31) * 128, m0 = (bb >> 5) * 128;
        Ap = hidb + (long)m0 * 2048;
        Bp = wq + (long)n0 * 2048;
        Cp = qbf + (long)m0 * 4096 + n0;
        ldc = 4096;
    }
    gemm128_f32b<__bf16>(Ap, Bp, Cp, 2048, 2048, 2048, ldc);
}

// ---------------------------------------------------------------------------
// Output projection, split-K=4 (512 blocks), fp32 partials.
// ---------------------------------------------------------------------------
__global__ __launch_bounds__(256) void gemm_wo_splitk(const __bf16* __restrict__ A,
                                                      const float* __restrict__ B,
                                                      float* __restrict__ po) {
    const int m0 = blockIdx.y * 128;
    const int n0 = blockIdx.x * 128;
    const int koff = blockIdx.z * 1024;
    float* C = po + (long)blockIdx.z * 1024 * 2048;
    gemm128_f32b<float>(A + (long)m0 * 4096 + koff, B + (long)n0 * 4096 + koff,
                        C + (long)m0 * 2048 + n0, 1024, 4096, 4096, 2048);
}

__global__ __launch_bounds__(256) void add4(const float* __restrict__ po,
                                            float* __restrict__ out, int n4) {
    int i = blockIdx.x * 256 + threadIdx.x;
    int stride = gridDim.x * 256;
    const long seg = (long)1024 * 2048 / 4;
    for (; i < n4; i += stride) {
        float4 a = ((const float4*)po)[i];
        float4 b = ((const float4*)po)[i + seg];
        float4 c = ((const float4*)po)[i + 2 * seg];
        float4 d = ((const float4*)po)[i + 3 * seg];
        float4 o;
        o.x = (a.x + b.x) + (c.x + d.x);
        o.y = (a.y + b.y) + (c.y + d.y);
        o.z = (a.z + b.z) + (c.z + d.z);
        o.w = (a.w + b.w) + (c.w + d.w);
        ((float4*)out)[i] = o;
    }
}

// ---------------------------------------------------------------------------
// Fused RMSNorm+RoPE for q (z=0) and k (z=1), in place.
// ---------------------------------------------------------------------------
__global__ __launch_bounds__(256) void rmsnorm_rope2(__bf16* __restrict__ xq,
                                                     const float* __restrict__ wq,
                                                     __bf16* __restrict__ xk,
                                                     const float* __restrict__ wk,
                                                     const float* __restrict__ cosb,
                                                     const float* __restrict__ sinb) {
    const int z = blockIdx.y;
    __bf16*      x = z ? xk : xq;
    const float* w = z ? wk : wq;
    const int nheads     = z ? 8 : 32;
    const int row_stride = z ? 1024 : 4096;
    const int pos_offset = z ? 0 : 2048;
    const float outscale = z ? 1.0f : 0.08838834764831845f;
    const int nitems     = z ? 3072 * 8 : 1024 * 32;

    int item = blockIdx.x * 4 + (threadIdx.x >> 6);
    int lane = threadIdx.x & 63;
    if (item >= nitems) return;
    int row = item / nheads;
    int head = item - row * nheads;
    __bf16* p = x + (long)row * row_stride + head * HD;

    float x1 = (float)p[lane], x2 = (float)p[lane + 64];
    float ss = x1 * x1 + x2 * x2;
#pragma unroll
    for (int o = 32; o >= 1; o >>= 1) ss += __shfl_xor(ss, o);
    float r = rsqrtf(ss * (1.0f / 128.0f) + 1e-6f) * outscale;

    int pos = pos_offset + row;
    float c1 = cosb[pos * HD + lane], c2 = cosb[pos * HD + lane + 64];
    float s1 = sinb[pos * HD + lane], s2 = sinb[pos * HD + lane + 64];
    float y1 = x1 * r * w[lane];
    float y2 = x2 * r * w[lane + 64];
    p[lane]      = (__bf16)(y1 * c1 - y2 * s1);
    p[lane + 64] = (__bf16)(y2 * c2 + y1 * s2);
}

// ---------------------------------------------------------------------------
// V transpose: vbf[t][g*128+d] -> vt[g][d][t]
// ---------------------------------------------------------------------------
__global__ __launch_bounds__(256) void transpose_v(const __bf16* __restrict__ v,
                                                   __bf16* __restrict__ vt) {
    __shared__ __bf16 T[64][68];
    const int tid = threadIdx.x;
    const int t0 = blockIdx.x * 64;
    const int d0 = blockIdx.y * 64;
    const int g  = blockIdx.z;
    const __bf16* src = v + (long)t0 * 1024 + g * 128 + d0;
#pragma unroll
    for (int i = 0; i < 4; i++) {
        int idx = tid + i * 256;
        int r = idx >> 4, c4 = (idx & 15) * 4;
        *(bf16x4*)&T[r][c4] = *(const bf16x4*)(src + (long)r * 1024 + c4);
    }
    __syncthreads();
    __bf16* dst = vt + (long)g * 128 * 3072 + (long)d0 * 3072 + t0;
#pragma unroll
    for (int i = 0; i < 4; i++) {
        int idx = tid + i * 256;
        int r = idx >> 4, c4 = (idx & 15) * 4;
        bf16x4 o;
        o[0] = T[c4 + 0][r]; o[1] = T[c4 + 1][r];
        o[2] = T[c4 + 2][r]; o[3] = T[c4 + 3][r];
        *(bf16x4*)(dst + (long)r * 3072 + c4) = o;
    }
}

// ---------------------------------------------------------------------------
// Split-K flash attention, 128 q-rows per block (4 waves x 2 m-tiles of 16).
// Staged K/V fragments are reused across both m-tiles (2x MFMA per LDS read).
// Fixed softmax shift; additive split-K merge. Ps aliases Ks (stride 68).
// ---------------------------------------------------------------------------
__global__ __launch_bounds__(256) void flash_attn_splitk(const __bf16* __restrict__ qb,
                                                         const __bf16* __restrict__ kb,
                                                         const __bf16* __restrict__ vtg,
                                                         __bf16* __restrict__ Opart0,
                                                         __bf16* __restrict__ Opart1,
                                                         float* __restrict__ lsum) {
    __shared__ __bf16 KsU[64 * 136];   // Ks[t][d] stride 136; Ps aliased (4*32*68 = 8704)
    __shared__ __bf16 Vs[128][72];     // [d][t]
#define KS(r, c) KsU[(r) * 136 + (c)]
#define PS(w_, m_, t_) KsU[(w_) * 2176 + (m_) * 68 + (t_)]

    const int tid  = threadIdx.x;
    const int lane = tid & 63;
    const int w    = tid >> 6;
    const int n    = lane & 15;
    const int quad = lane >> 4;

    const int bid = blockIdx.x;        // 0..255
    const int s   = blockIdx.y;
    const int g  = bid & 7;
    const int jj = bid >> 3;           // 0..31
    const int h  = g * 4 + (jj & 3);
    const int qt = jj >> 2;            // 0..7, 128-row q tiles

    const int qr0 = qt * 128 + w * 16; // m-tile 0 base; m-tile 1 = +64

    bf16x8 qf[2][4];
#pragma unroll
    for (int mt = 0; mt < 2; mt++) {
        const __bf16* qp = qb + (long)(qr0 + mt * 64 + n) * 4096 + h * 128 + quad * 8;
        qf[mt][0] = *(const bf16x8*)(qp);
        qf[mt][1] = *(const bf16x8*)(qp + 32);
        qf[mt][2] = *(const bf16x8*)(qp + 64);
        qf[mt][3] = *(const bf16x8*)(qp + 96);
    }

    f32x4 O[2][8];
    const f32x4 fzero = {0.f, 0.f, 0.f, 0.f};
#pragma unroll
    for (int mt = 0; mt < 2; mt++)
#pragma unroll
        for (int dt = 0; dt < 8; dt++) O[mt][dt] = fzero;
    float l_loc[2][4] = {{0.f, 0.f, 0.f, 0.f}, {0.f, 0.f, 0.f, 0.f}};

    const int ntot = 34 + 2 * qt;      // even
    const int half = ntot >> 1;
    const int tbeg = s ? half : 0;
    const int tend = s ? ntot : half;

    const int krr = tid >> 4, kc8 = (tid & 15) * 8;
    const int vrr = tid >> 3, vc8 = (tid & 7) * 8;
    const __bf16* kp = kb + g * 128 + (long)(tbeg * 64 + krr) * 1024 + kc8;
    const __bf16* vp = vtg + (long)g * 128 * 3072 + (long)vrr * 3072 + tbeg * 64 + vc8;

    for (int tt = tbeg; tt < tend; tt++) {
#pragma unroll
        for (int i = 0; i < 4; i++)
            *(bf16x8*)&KS(krr + i * 16, kc8) = *(const bf16x8*)(kp + (long)i * 16 * 1024);
#pragma unroll
        for (int i = 0; i < 4; i++)
            *(bf16x8*)&Vs[vrr + i * 32][vc8] = *(const bf16x8*)(vp + (long)i * 32 * 3072);
        kp += 64 * 1024;
        vp += 64;
        __syncthreads();

        // S = Q K^T, both m-tiles share each staged K fragment
        f32x4 S[2][4];
#pragma unroll
        for (int nt = 0; nt < 4; nt++) {
            f32x4 a0 = fzero, a1 = fzero;
#pragma unroll
            for (int ks = 0; ks < 4; ks++) {
                bf16x8 bfr = *(const bf16x8*)&KS(nt * 16 + n, ks * 32 + quad * 8);
                a0 = MFMA16(qf[0][ks], bfr, a0);
                a1 = MFMA16(qf[1][ks], bfr, a1);
            }
            S[0][nt] = a0;
            S[1][nt] = a1;
        }

        if (tt >= ntot - 2) {   // diagonal band spans the last two tiles
            const int t0 = tt * 64;
#pragma unroll
            for (int mt = 0; mt < 2; mt++)
#pragma unroll
                for (int nt = 0; nt < 4; nt++)
#pragma unroll
                    for (int r = 0; r < 4; r++) {
                        int t   = t0 + nt * 16 + n;
                        int lim = 2048 + qr0 + mt * 64 + quad * 4 + r;
                        if (t > lim) S[mt][nt][r] = -1e30f;
                    }
        }

        __syncthreads();   // all Ks reads done; Ps may overwrite

#pragma unroll
        for (int mt = 0; mt < 2; mt++)
#pragma unroll
            for (int nt = 0; nt < 4; nt++)
#pragma unroll
                for (int r = 0; r < 4; r++) {
                    float p = __expf(S[mt][nt][r] - MSTATIC);
                    S[mt][nt][r] = p;
                    l_loc[mt][r] += p;
                }

#pragma unroll
        for (int mt = 0; mt < 2; mt++)
#pragma unroll
            for (int nt = 0; nt < 4; nt++)
#pragma unroll
                for (int r = 0; r < 4; r++)
                    PS(w, mt * 16 + quad * 4 + r, nt * 16 + n) = (__bf16)S[mt][nt][r];

        bf16x8 pa[2][2];
#pragma unroll
        for (int mt = 0; mt < 2; mt++)
#pragma unroll
            for (int kg = 0; kg < 2; kg++)
                pa[mt][kg] = *(const bf16x8*)&PS(w, mt * 16 + n, kg * 32 + quad * 8);

#pragma unroll
        for (int dt = 0; dt < 8; dt++) {
            bf16x8 vf0 = *(const bf16x8*)&Vs[dt * 16 + n][quad * 8];
            bf16x8 vf1 = *(const bf16x8*)&Vs[dt * 16 + n][32 + quad * 8];
#pragma unroll
            for (int mt = 0; mt < 2; mt++) {
                f32x4 acc = O[mt][dt];
                acc = MFMA16(pa[mt][0], vf0, acc);
                acc = MFMA16(pa[mt][1], vf1, acc);
                O[mt][dt] = acc;
            }
        }
        __syncthreads();
    }

    // row-sum reduction across the 16 n-lanes, once per block
#pragma unroll
    for (int mt = 0; mt < 2; mt++)
#pragma unroll
        for (int r = 0; r < 4; r++) {
            float sm = l_loc[mt][r];
            sm += __shfl_xor(sm, 1);
            sm += __shfl_xor(sm, 2);
            sm += __shfl_xor(sm, 4);
            sm += __shfl_xor(sm, 8);
            l_loc[mt][r] = sm;
        }

    __bf16* Op = s ? Opart1 : Opart0;
    const long tb = (long)(h * 8 + qt) * 128 * 128;
#pragma unroll
    for (int mt = 0; mt < 2; mt++)
#pragma unroll
        for (int dt = 0; dt < 8; dt++)
#pragma unroll
            for (int r = 0; r < 4; r++)
                Op[tb + (long)(mt * 64 + w * 16 + quad * 4 + r) * 128 + dt * 16 + n] =
                    (__bf16)O[mt][dt][r];
    if (n == 0) {
        const int lb = (s * 256 + h * 8 + qt) * 128 + w * 16 + quad * 4;
#pragma unroll
        for (int mt = 0; mt < 2; mt++)
#pragma unroll
            for (int r = 0; r < 4; r++)
                lsum[lb + mt * 64 + r] = l_loc[mt][r];
    }
#undef KS
#undef PS
}

// ---------------------------------------------------------------------------
// Additive merge of split-K partials -> normalized bf16 O over qbf.
// ---------------------------------------------------------------------------
__global__ __launch_bounds__(256) void flash_merge(const __bf16* __restrict__ O0,
                                                   const __bf16* __restrict__ O1,
                                                   const float* __restrict__ lsum,
                                                   __bf16* __restrict__ ob) {
    const int bx = blockIdx.x;         // 512: (h, qt, half64)
    const int h   = bx >> 4;
    const int r6  = bx & 15;
    const int qt  = r6 >> 1;
    const int sub = r6 & 1;
    const int row  = threadIdx.x >> 2;
    const int cseg = (threadIdx.x & 3) * 32;
    const int mrow = sub * 64 + row;

    const int tilei = h * 8 + qt;
    float inv = 1.0f / (lsum[tilei * 128 + mrow] + lsum[(256 + tilei) * 128 + mrow]);

    const long src = (long)tilei * 128 * 128 + (long)mrow * 128 + cseg;
    __bf16* dst = ob + (long)(qt * 128 + mrow) * 4096 + h * 128 + cseg;
#pragma unroll
    for (int j = 0; j < 4; j++) {
        bf16x8 x0 = *(const bf16x8*)(O0 + src + j * 8);
        bf16x8 x1 = *(const bf16x8*)(O1 + src + j * 8);
        bf16x8 o;
#pragma unroll
        for (int k = 0; k < 8; k++)
            o[k] = (__bf16)(((float)x0[k] + (float)x1[k]) * inv);
        *(bf16x8*)(dst + j * 8) = o;
    }
}

// ---------------------------------------------------------------------------
extern "C" void kernel_launch(void* const* d_in, const int* in_sizes, int n_in,
                              void* d_out, int out_size, void* d_ws, size_t ws_size,
                              hipStream_t stream) {
    const float* hidden = (const float*)d_in[0];
    const float* target = (const float*)d_in[1];
    const float* cosb   = (const float*)d_in[2];
    const float* sinb   = (const float*)d_in[3];
    const float* wq = (const float*)d_in[5];
    const float* wk = (const float*)d_in[6];
    const float* wv = (const float*)d_in[7];
    const float* wo = (const float*)d_in[8];
    const float* qw = (const float*)d_in[9];
    const float* kw = (const float*)d_in[10];
    float* out = (float*)d_out;

    // 40 MB workspace, phased overlays (launch order guarantees safety):
    char* ws = (char*)d_ws;
    const long MB = 1 << 20;
    __bf16* qbf  = (__bf16*)(ws);             // @0..8    q / attn out (live throughout)
    __bf16* kbf  = (__bf16*)(ws + 8 * MB);    // @8..14   k (dead after flash)
    __bf16* vbf  = (__bf16*)(ws + 14 * MB);   // @14..20  v (dead after transpose)
    __bf16* hidb = (__bf16*)(ws + 20 * MB);   // @20..24  (dead after gemm_kvq)
    __bf16* tgtb = (__bf16*)(ws + 24 * MB);   // @24..32  (dead after gemm_kvq)
    __bf16* vtg  = (__bf16*)(ws + 24 * MB);   // @24..30  (post-kvq)
    __bf16* Op1  = (__bf16*)(ws + 14 * MB);   // @14..22  (post-transpose)
    float*  lbuf = (float*)(ws + 22 * MB);    // @22..22.25
    __bf16* Op0  = (__bf16*)(ws + 30 * MB);   // @30..38
    float*  po   = (float*)(ws + 8 * MB);     // @8..40   wo partials (post-merge)

    dim3 blk(256);

    // activations -> bf16
    conv2_f32_bf16<<<dim3(1024, 2), blk, 0, stream>>>(
        target, tgtb, (2048 * 2048) / 4, hidden, hidb, (1024 * 2048) / 4);

    // all three projections, one launch (weights stay fp32, converted in-GEMM)
    gemm_kvq<<<640, blk, 0, stream>>>(tgtb, hidb, wk, wv, wq, kbf, vbf, qbf);

    // fused RMSNorm + RoPE (q and k)
    rmsnorm_rope2<<<dim3(8192, 2), blk, 0, stream>>>(qbf, qw, kbf, kw, cosb, sinb);

    // V transpose -> [g][d][t]
    transpose_v<<<dim3(48, 2, 8), blk, 0, stream>>>(vbf, vtg);

    // split-K flash attention (512 blocks, 128 q-rows each) + additive merge
    flash_attn_splitk<<<dim3(256, 2), blk, 0, stream>>>(qbf, kbf, vtg, Op0, Op1, lbuf);
    flash_merge<<<512, blk, 0, stream>>>(Op0, Op1, lbuf, qbf);

    // output projection: split-K=4 (512 blocks) + reduce
    gemm_wo_splitk<<<dim3(16, 8, 4), blk, 0, stream>>>(qbf, wo, po);
    add4<<<1024, blk, 0, stream>>>(po, out, (1024 * 2048) / 4);
}